// Round 1
// baseline (793.583 us; speedup 1.0000x reference)
//
#include <hip/hip_runtime.h>
#include <hip/hip_bf16.h>

#define EPS 1e-5f
#define NSf 65536.0f

// ---------------- workspace layout (float offsets) ----------------
#define WS_Y2    0                        // 8*128*8192 = 8388608 floats (32MB)
#define WS_SRCM  8388608                  // 9 used (ssum[3], ss[6]); pad 16
#define WS_EFF1  (WS_SRCM + 16)           // w1eff[192], b1eff[64] -> 256
#define WS_S2    (WS_EFF1 + 256)          // s2sum[128], s2sq[128]
#define WS_SC2   (WS_S2 + 256)            // scale2[128], shift2[128]
#define WS_S3    (WS_SC2 + 256)           // s3sum[1024], s3sq[1024]
#define WS_PMAX  (WS_S3 + 2048)           // 8192 mapped-uint
#define WS_PMIN  (WS_PMAX + 8192)         // 8192 mapped-uint
#define WS_POOL  (WS_PMIN + 8192)         // 8192
#define WS_FC1   (WS_POOL + 8192)         // 4096
#define WS_FC2   (WS_FC1 + 4096)          // 2048
#define WS_ROT   (WS_FC2 + 2048)          // 72
#define WS_TRANS (WS_ROT + 72)            // 24
#define WS_DIST  (WS_TRANS + 24)          // 72
#define WS_END   (WS_DIST + 72)

__device__ __forceinline__ unsigned fmap(float f) {
  unsigned u = __float_as_uint(f);
  return (u & 0x80000000u) ? ~u : (u | 0x80000000u);
}
__device__ __forceinline__ float funmap(unsigned u) {
  return __uint_as_float((u & 0x80000000u) ? (u ^ 0x80000000u) : ~u);
}

// ---------------- K0: init accumulators ----------------
__global__ void k_init(float* ws) {
  int idx = blockIdx.x * 256 + threadIdx.x;
  int total = WS_END - WS_SRCM;
  if (idx < total) {
    int a = WS_SRCM + idx;
    unsigned val = 0u;
    if (a >= WS_PMIN && a < WS_PMIN + 8192) val = 0xFFFFFFFFu;
    ((unsigned*)ws)[a] = val;
  }
}

// ---------------- K1: source moments (for layer-1 BN stats) ----------------
__global__ void k_stats_src(const float* __restrict__ src, float* __restrict__ M) {
  int t = blockIdx.x * 256 + threadIdx.x;     // 0..65535  (b,n)
  int b = t >> 13, n = t & 8191;
  float s0 = src[(b * 3 + 0) * 8192 + n];
  float s1 = src[(b * 3 + 1) * 8192 + n];
  float s2 = src[(b * 3 + 2) * 8192 + n];
  float p[9] = {s0, s1, s2, s0 * s0, s0 * s1, s0 * s2, s1 * s1, s1 * s2, s2 * s2};
#pragma unroll
  for (int i = 0; i < 9; ++i)
    for (int off = 32; off; off >>= 1) p[i] += __shfl_xor(p[i], off);
  if ((threadIdx.x & 63) == 0) {
#pragma unroll
    for (int i = 0; i < 9; ++i) atomicAdd(&M[i], p[i]);
  }
}

// ---------------- K2: finalize layer-1 BN -> effective conv1 weights ----------------
__global__ void k_fin1(const float* __restrict__ M, const float* __restrict__ w1,
                       const float* __restrict__ b1, const float* __restrict__ g1,
                       const float* __restrict__ be1, float* __restrict__ eff) {
  int c = threadIdx.x;  // 64
  float s0 = M[0], s1 = M[1], s2 = M[2];
  float ss00 = M[3], ss01 = M[4], ss02 = M[5], ss11 = M[6], ss12 = M[7], ss22 = M[8];
  float a0 = w1[c * 3], a1 = w1[c * 3 + 1], a2 = w1[c * 3 + 2], bb = b1[c];
  float dotS = a0 * s0 + a1 * s1 + a2 * s2;
  float sumY = dotS + NSf * bb;
  float sumY2 = a0 * a0 * ss00 + a1 * a1 * ss11 + a2 * a2 * ss22
              + 2.f * (a0 * a1 * ss01 + a0 * a2 * ss02 + a1 * a2 * ss12)
              + 2.f * bb * dotS + NSf * bb * bb;
  float m = sumY / NSf;
  float v = sumY2 / NSf - m * m;
  float sc = g1[c] * rsqrtf(v + EPS);
  float sh = be1[c] - m * sc;
  eff[c * 3 + 0] = sc * a0;
  eff[c * 3 + 1] = sc * a1;
  eff[c * 3 + 2] = sc * a2;
  eff[192 + c] = sc * bb + sh;
}

// ---------------- K3: conv2 (x1 recomputed on the fly), writes y2 ----------------
__global__ __launch_bounds__(256) void k_conv2(const float* __restrict__ src,
                                               const float* __restrict__ eff,
                                               const float* __restrict__ w2,
                                               const float* __restrict__ b2,
                                               float* __restrict__ y2) {
  int bx = blockIdx.x, t = threadIdx.x;
  int b = bx >> 5;                     // 32 blocks per batch
  int n = ((bx & 31) << 8) + t;
  float s0 = src[(b * 3 + 0) * 8192 + n];
  float s1 = src[(b * 3 + 1) * 8192 + n];
  float s2 = src[(b * 3 + 2) * 8192 + n];
  float x1[64];
#pragma unroll
  for (int c = 0; c < 64; ++c)
    x1[c] = fmaxf(fmaf(eff[c * 3], s0, fmaf(eff[c * 3 + 1], s1,
                  fmaf(eff[c * 3 + 2], s2, eff[192 + c]))), 0.f);
  size_t base = ((size_t)b * 128) * 8192 + n;
  for (int o = 0; o < 128; ++o) {
    float acc = b2[o];
#pragma unroll
    for (int c = 0; c < 64; ++c) acc = fmaf(w2[o * 64 + c], x1[c], acc);
    y2[base + (size_t)o * 8192] = acc;
  }
}

// ---------------- K4: layer-2 BN stats (one block per channel) ----------------
__global__ void k_stats2(const float* __restrict__ y2, float* __restrict__ S2) {
  int o = blockIdx.x, t = threadIdx.x;
  float s = 0.f, q = 0.f;
  for (int b = 0; b < 8; ++b) {
    const float* p = y2 + ((size_t)(b * 128 + o)) * 8192;
    for (int k = t; k < 8192; k += 256) {
      float v = p[k];
      s += v;
      q = fmaf(v, v, q);
    }
  }
  for (int off = 32; off; off >>= 1) {
    s += __shfl_xor(s, off);
    q += __shfl_xor(q, off);
  }
  __shared__ float ls[4][2];
  int w = t >> 6, lane = t & 63;
  if (lane == 0) { ls[w][0] = s; ls[w][1] = q; }
  __syncthreads();
  if (t == 0) {
    float S = 0.f, Q = 0.f;
    for (int i = 0; i < 4; ++i) { S += ls[i][0]; Q += ls[i][1]; }
    S2[o] = S;
    S2[128 + o] = Q;
  }
}

// ---------------- K5: finalize layer-2 BN scale/shift ----------------
__global__ void k_fin2(const float* __restrict__ S2, const float* __restrict__ g2,
                       const float* __restrict__ be2, float* __restrict__ SC2) {
  int o = threadIdx.x;  // 128
  float m = S2[o] / NSf;
  float v = S2[128 + o] / NSf - m * m;
  float sc = g2[o] * rsqrtf(v + EPS);
  SC2[o] = sc;
  SC2[128 + o] = be2[o] - m * sc;
}

// ---------------- K6: conv3 + layer-3 stats + max/min pool (y3 never stored) ----
__global__ __launch_bounds__(512) void k_conv3(const float* __restrict__ y2,
                                               const float* __restrict__ sc2,
                                               const float* __restrict__ w3,
                                               const float* __restrict__ b3,
                                               float* __restrict__ S3,
                                               float* __restrict__ PMAXf,
                                               float* __restrict__ PMINf) {
  __shared__ float xs[128 * 128];  // 64KB: x2 tile [c=128][n=128]
  int bx = blockIdx.x;
  int ob = bx & 7, cb = bx >> 3;
  int o0 = ob * 128;
  int b = cb >> 6;                 // 64 col-tiles per batch
  int n0 = (cb & 63) << 7;
  int t = threadIdx.x;
  // stage x2 tile with BN2+ReLU applied
#pragma unroll
  for (int i = 0; i < 8; ++i) {
    int fidx = i * 2048 + t * 4;
    int c = fidx >> 7, nn = fidx & 127;
    const float4 v = *(const float4*)&y2[((size_t)(b * 128 + c)) * 8192 + n0 + nn];
    float sc = sc2[c], sh = sc2[128 + c];
    float4 x;
    x.x = fmaxf(fmaf(sc, v.x, sh), 0.f);
    x.y = fmaxf(fmaf(sc, v.y, sh), 0.f);
    x.z = fmaxf(fmaf(sc, v.z, sh), 0.f);
    x.w = fmaxf(fmaf(sc, v.w, sh), 0.f);
    *(float4*)&xs[c * 128 + nn] = x;
  }
  __syncthreads();
  int lane = t & 63;
  int wv = __builtin_amdgcn_readfirstlane(t >> 6);  // wave id 0..7 (SGPR)
  const float* w3w = w3 + (size_t)(o0 + wv * 16) * 128;  // wave-uniform -> s_load path
  float2 acc[16];
#pragma unroll
  for (int i = 0; i < 16; ++i) acc[i] = make_float2(0.f, 0.f);
#pragma unroll 4
  for (int k = 0; k < 128; ++k) {
    float2 xv = *(const float2*)&xs[k * 128 + lane * 2];
#pragma unroll
    for (int i = 0; i < 16; ++i) {
      float w = w3w[i * 128 + k];
      acc[i].x = fmaf(w, xv.x, acc[i].x);
      acc[i].y = fmaf(w, xv.y, acc[i].y);
    }
  }
#pragma unroll
  for (int i = 0; i < 16; ++i) {
    int o = o0 + wv * 16 + i;
    float bias = b3[o];
    float v0 = acc[i].x + bias, v1 = acc[i].y + bias;
    float s = v0 + v1;
    float q = fmaf(v0, v0, v1 * v1);
    float mx = fmaxf(v0, v1), mn = fminf(v0, v1);
    for (int off = 32; off; off >>= 1) {
      s += __shfl_xor(s, off);
      q += __shfl_xor(q, off);
      mx = fmaxf(mx, __shfl_xor(mx, off));
      mn = fminf(mn, __shfl_xor(mn, off));
    }
    if (lane == 0) {
      atomicAdd(&S3[o], s);
      atomicAdd(&S3[1024 + o], q);
      atomicMax((unsigned*)&PMAXf[b * 1024 + o], fmap(mx));
      atomicMin((unsigned*)&PMINf[b * 1024 + o], fmap(mn));
    }
  }
}

// ---------------- K7: finalize layer-3 BN + pooled = relu(bn(max-or-min)) -----
__global__ void k_pool(const float* __restrict__ S3, const float* __restrict__ g3,
                       const float* __restrict__ be3, const float* __restrict__ PMAXf,
                       const float* __restrict__ PMINf, float* __restrict__ POOL) {
  int idx = blockIdx.x * 256 + threadIdx.x;  // b*1024+o, 8192 total
  int o = idx & 1023;
  float m = S3[o] / NSf;
  float v = S3[1024 + o] / NSf - m * m;
  float sc = g3[o] * rsqrtf(v + EPS);
  float sh = be3[o] - m * sc;
  float mx = funmap(((const unsigned*)PMAXf)[idx]);
  float mn = funmap(((const unsigned*)PMINf)[idx]);
  float z = (sc >= 0.f) ? fmaf(sc, mx, sh) : fmaf(sc, mn, sh);
  POOL[idx] = fmaxf(z, 0.f);
}

// ---------------- K8/K9: FC + BN(batch of 8) + ReLU, one wave per out channel --
__global__ void k_fc(const float* __restrict__ xin, const float* __restrict__ w,
                     const float* __restrict__ bias, const float* __restrict__ g,
                     const float* __restrict__ be, float* __restrict__ out,
                     int K, int O) {
  int o = blockIdx.x, lane = threadIdx.x;  // 64 threads
  float yb[8] = {0.f, 0.f, 0.f, 0.f, 0.f, 0.f, 0.f, 0.f};
  for (int j = 0; j < K; j += 64) {
    float wv = w[(size_t)o * K + j + lane];
#pragma unroll
    for (int b = 0; b < 8; ++b) yb[b] = fmaf(wv, xin[b * K + j + lane], yb[b]);
  }
#pragma unroll
  for (int b = 0; b < 8; ++b)
    for (int off = 32; off; off >>= 1) yb[b] += __shfl_xor(yb[b], off);
  if (lane == 0) {
    float y[8];
    float m = 0.f;
#pragma unroll
    for (int b = 0; b < 8; ++b) { y[b] = yb[b] + bias[o]; m += y[b]; }
    m *= 0.125f;
    float v = 0.f;
#pragma unroll
    for (int b = 0; b < 8; ++b) { float d = y[b] - m; v = fmaf(d, d, v); }
    v *= 0.125f;
    float sc = g[o] * rsqrtf(v + EPS);
    float sh = be[o] - m * sc;
#pragma unroll
    for (int b = 0; b < 8; ++b) out[b * O + o] = fmaxf(fmaf(sc, y[b], sh), 0.f);
  }
}

// ---------------- K10: rot (+eye) and trans heads ----------------
__global__ void k_rot(const float* __restrict__ x, const float* __restrict__ wr,
                      const float* __restrict__ br, const float* __restrict__ wt,
                      const float* __restrict__ bt, float* __restrict__ ROT,
                      float* __restrict__ TRANS) {
  int q = blockIdx.x;  // 96 = 8b * 12
  int b = q / 12, j = q % 12;
  int lane = threadIdx.x;
  float p = 0.f;
#pragma unroll
  for (int i = 0; i < 4; ++i) {
    int kk = i * 64 + lane;
    float w = (j < 9) ? wr[j * 256 + kk] : wt[(j - 9) * 256 + kk];
    p = fmaf(w, x[b * 256 + kk], p);
  }
  for (int off = 32; off; off >>= 1) p += __shfl_xor(p, off);
  if (lane == 0) {
    if (j < 9)
      ROT[b * 9 + j] = p + br[j] + ((j == 0 || j == 4 || j == 8) ? 1.f : 0.f);
    else
      TRANS[b * 3 + (j - 9)] = p + bt[j - 9];
  }
}

// ---------------- K11: apply transform, write st, accumulate dist[b][3][3] ----
__global__ void k_transform(const float* __restrict__ src, const float* __restrict__ tgt,
                            const float* __restrict__ ROT, const float* __restrict__ TRANS,
                            float* __restrict__ out, float* __restrict__ DIST) {
  int bx = blockIdx.x, t = threadIdx.x;
  int b = bx >> 5;
  int n = ((bx & 31) << 8) + t;
  float s0 = src[(b * 3 + 0) * 8192 + n];
  float s1 = src[(b * 3 + 1) * 8192 + n];
  float s2 = src[(b * 3 + 2) * 8192 + n];
  const float* R = ROT + b * 9;
  const float* T = TRANS + b * 3;
  float st[3];
#pragma unroll
  for (int c = 0; c < 3; ++c) {
    st[c] = fmaf(s0, R[0 * 3 + c], fmaf(s1, R[1 * 3 + c], fmaf(s2, R[2 * 3 + c], T[c])));
    out[1 + (b * 3 + c) * 8192 + n] = st[c];
  }
  float tg[3];
#pragma unroll
  for (int i = 0; i < 3; ++i) tg[i] = tgt[(b * 3 + i) * 8192 + n];
  float d[9];
#pragma unroll
  for (int i = 0; i < 3; ++i)
#pragma unroll
    for (int j = 0; j < 3; ++j) {
      float df = st[j] - tg[i];
      d[i * 3 + j] = df * df;
    }
#pragma unroll
  for (int k = 0; k < 9; ++k)
    for (int off = 32; off; off >>= 1) d[k] += __shfl_xor(d[k], off);
  if ((t & 63) == 0) {
#pragma unroll
    for (int k = 0; k < 9; ++k) atomicAdd(&DIST[b * 9 + k], d[k]);
  }
}

// ---------------- K12: loss ----------------
__global__ void k_loss(const float* __restrict__ DIST, float* __restrict__ out) {
  if (threadIdx.x == 0 && blockIdx.x == 0) {
    float acc = 0.f;
    for (int b = 0; b < 8; ++b) {
      const float* D = DIST + b * 9;
      for (int j = 0; j < 3; ++j)
        acc += fminf(D[j], fminf(D[3 + j], D[6 + j]));       // min over i
      for (int i = 0; i < 3; ++i)
        acc += fminf(D[i * 3], fminf(D[i * 3 + 1], D[i * 3 + 2]));  // min over j
    }
    out[0] = acc / 24.f;
  }
}

extern "C" void kernel_launch(void* const* d_in, const int* in_sizes, int n_in,
                              void* d_out, int out_size, void* d_ws, size_t ws_size,
                              hipStream_t stream) {
  const float* src = (const float*)d_in[0];
  const float* tgt = (const float*)d_in[1];
  const float* w1 = (const float*)d_in[2];
  const float* b1 = (const float*)d_in[3];
  const float* w2 = (const float*)d_in[4];
  const float* b2 = (const float*)d_in[5];
  const float* w3 = (const float*)d_in[6];
  const float* b3 = (const float*)d_in[7];
  const float* fw1 = (const float*)d_in[8];
  const float* fb1 = (const float*)d_in[9];
  const float* fw2 = (const float*)d_in[10];
  const float* fb2 = (const float*)d_in[11];
  const float* wr = (const float*)d_in[12];
  const float* br = (const float*)d_in[13];
  const float* wt = (const float*)d_in[14];
  const float* bt = (const float*)d_in[15];
  const float* g1 = (const float*)d_in[16];
  const float* be1 = (const float*)d_in[17];
  const float* g2 = (const float*)d_in[18];
  const float* be2 = (const float*)d_in[19];
  const float* g3 = (const float*)d_in[20];
  const float* be3 = (const float*)d_in[21];
  const float* g4 = (const float*)d_in[22];
  const float* be4 = (const float*)d_in[23];
  const float* g5 = (const float*)d_in[24];
  const float* be5 = (const float*)d_in[25];
  float* out = (float*)d_out;
  float* ws = (float*)d_ws;

  k_init<<<(WS_END - WS_SRCM + 255) / 256, 256, 0, stream>>>(ws);
  k_stats_src<<<256, 256, 0, stream>>>(src, ws + WS_SRCM);
  k_fin1<<<1, 64, 0, stream>>>(ws + WS_SRCM, w1, b1, g1, be1, ws + WS_EFF1);
  k_conv2<<<256, 256, 0, stream>>>(src, ws + WS_EFF1, w2, b2, ws + WS_Y2);
  k_stats2<<<128, 256, 0, stream>>>(ws + WS_Y2, ws + WS_S2);
  k_fin2<<<1, 128, 0, stream>>>(ws + WS_S2, g2, be2, ws + WS_SC2);
  k_conv3<<<4096, 512, 0, stream>>>(ws + WS_Y2, ws + WS_SC2, w3, b3,
                                    ws + WS_S3, ws + WS_PMAX, ws + WS_PMIN);
  k_pool<<<32, 256, 0, stream>>>(ws + WS_S3, g3, be3, ws + WS_PMAX, ws + WS_PMIN,
                                 ws + WS_POOL);
  k_fc<<<512, 64, 0, stream>>>(ws + WS_POOL, fw1, fb1, g4, be4, ws + WS_FC1, 1024, 512);
  k_fc<<<256, 64, 0, stream>>>(ws + WS_FC1, fw2, fb2, g5, be5, ws + WS_FC2, 512, 256);
  k_rot<<<96, 64, 0, stream>>>(ws + WS_FC2, wr, br, wt, bt, ws + WS_ROT, ws + WS_TRANS);
  k_transform<<<256, 256, 0, stream>>>(src, tgt, ws + WS_ROT, ws + WS_TRANS, out,
                                       ws + WS_DIST);
  k_loss<<<1, 64, 0, stream>>>(ws + WS_DIST, out);
}

// Round 2
// 450.497 us; speedup vs baseline: 1.7616x; 1.7616x over previous
//
#include <hip/hip_runtime.h>
#include <hip/hip_bf16.h>

#define EPS 1e-5f
#define NSf 65536.0f

typedef unsigned short u16;
typedef __attribute__((ext_vector_type(8))) unsigned short u16x8;
typedef __attribute__((ext_vector_type(8))) short bf16x8;
typedef __attribute__((ext_vector_type(4))) float f32x4;

// ---------------- workspace layout (float offsets) ----------------
#define WS_Y2T   0                         // 8,388,608 bf16 = 4,194,304 floats (in-place x2t)
#define WS_W3BF  4194304                   // 131072 bf16 = 65536 floats
#define WS_G     4259840                   // 16384 f32
#define WS_SRCM  4276224                   // 16
#define WS_EFF1  4276240                   // 256
#define WS_S2    4276496                   // 256
#define WS_SC2   4276752                   // 256
#define WS_CS    4277008                   // 128
#define WS_S3    4277136                   // 2048
#define WS_PMAX  4279184                   // 8192 mapped-uint
#define WS_POOL  4287376                   // 8192
#define WS_FC1   4295568                   // 4096
#define WS_FC2   4299664                   // 2048
#define WS_ROT   4301712                   // 72
#define WS_TRANS 4301784                   // 24
#define WS_DIST  4301808                   // 72
#define WS_END   4301880

__device__ __forceinline__ unsigned fmap(float f) {
  unsigned u = __float_as_uint(f);
  return (u & 0x80000000u) ? ~u : (u | 0x80000000u);
}
__device__ __forceinline__ float funmap(unsigned u) {
  return __uint_as_float((u & 0x80000000u) ? (u ^ 0x80000000u) : ~u);
}
__device__ __forceinline__ u16 f2b(float f) {
  unsigned u = __float_as_uint(f);
  u += 0x7FFFu + ((u >> 16) & 1);
  return (u16)(u >> 16);
}
__device__ __forceinline__ float b2f(u16 h) { return __uint_as_float(((unsigned)h) << 16); }

__device__ __forceinline__ void gl16(const void* g, void* l) {
  __builtin_amdgcn_global_load_lds((const __attribute__((address_space(1))) unsigned*)g,
                                   (__attribute__((address_space(3))) unsigned*)l, 16, 0, 0);
}

// ---------------- K0: init atomic accumulators ----------------
__global__ void k_init(float* ws) {
  int idx = blockIdx.x * 256 + threadIdx.x;
  int total = WS_END - WS_G;
  if (idx < total) ((unsigned*)ws)[WS_G + idx] = 0u;  // PMAX mapped-0 == lowest
}

// ---------------- K1: source moments (layer-1 BN stats) ----------------
__global__ void k_stats_src(const float* __restrict__ src, float* __restrict__ M) {
  int t = blockIdx.x * 256 + threadIdx.x;
  int b = t >> 13, n = t & 8191;
  float s0 = src[(b * 3 + 0) * 8192 + n];
  float s1 = src[(b * 3 + 1) * 8192 + n];
  float s2 = src[(b * 3 + 2) * 8192 + n];
  float p[9] = {s0, s1, s2, s0 * s0, s0 * s1, s0 * s2, s1 * s1, s1 * s2, s2 * s2};
#pragma unroll
  for (int i = 0; i < 9; ++i)
    for (int off = 32; off; off >>= 1) p[i] += __shfl_xor(p[i], off);
  if ((threadIdx.x & 63) == 0) {
#pragma unroll
    for (int i = 0; i < 9; ++i) atomicAdd(&M[i], p[i]);
  }
}

// ---------------- K2: finalize layer-1 BN -> effective conv1 weights ----------
__global__ void k_fin1(const float* __restrict__ M, const float* __restrict__ w1,
                       const float* __restrict__ b1, const float* __restrict__ g1,
                       const float* __restrict__ be1, float* __restrict__ eff) {
  int c = threadIdx.x;  // 64
  float s0 = M[0], s1 = M[1], s2 = M[2];
  float ss00 = M[3], ss01 = M[4], ss02 = M[5], ss11 = M[6], ss12 = M[7], ss22 = M[8];
  float a0 = w1[c * 3], a1 = w1[c * 3 + 1], a2 = w1[c * 3 + 2], bb = b1[c];
  float dotS = a0 * s0 + a1 * s1 + a2 * s2;
  float sumY = dotS + NSf * bb;
  float sumY2 = a0 * a0 * ss00 + a1 * a1 * ss11 + a2 * a2 * ss22
              + 2.f * (a0 * a1 * ss01 + a0 * a2 * ss02 + a1 * a2 * ss12)
              + 2.f * bb * dotS + NSf * bb * bb;
  float m = sumY / NSf;
  float v = sumY2 / NSf - m * m;
  float sc = g1[c] * rsqrtf(v + EPS);
  float sh = be1[c] - m * sc;
  eff[c * 3 + 0] = sc * a0;
  eff[c * 3 + 1] = sc * a1;
  eff[c * 3 + 2] = sc * a2;
  eff[192 + c] = sc * bb + sh;
}

// ---------------- K3: conv2 -> y2t[b][n][c] bf16 ----------------
__global__ __launch_bounds__(256) void k_conv2(const float* __restrict__ src,
                                               const float* __restrict__ eff,
                                               const float* __restrict__ w2,
                                               const float* __restrict__ b2,
                                               u16* __restrict__ y2t) {
  int bx = blockIdx.x, t = threadIdx.x;
  int b = bx >> 5;
  int n = ((bx & 31) << 8) + t;
  float s0 = src[(b * 3 + 0) * 8192 + n];
  float s1 = src[(b * 3 + 1) * 8192 + n];
  float s2 = src[(b * 3 + 2) * 8192 + n];
  float x1[64];
#pragma unroll
  for (int c = 0; c < 64; ++c)
    x1[c] = fmaxf(fmaf(eff[c * 3], s0, fmaf(eff[c * 3 + 1], s1,
                  fmaf(eff[c * 3 + 2], s2, eff[192 + c]))), 0.f);
  size_t pbase = ((size_t)(b * 8192 + n)) * 128;
  for (int og = 0; og < 16; ++og) {
    u16x8 pk;
#pragma unroll
    for (int e = 0; e < 8; ++e) {
      int o = og * 8 + e;
      float acc = b2[o];
#pragma unroll
      for (int c = 0; c < 64; ++c) acc = fmaf(w2[o * 64 + c], x1[c], acc);
      pk[e] = f2b(acc);
    }
    *(u16x8*)(y2t + pbase + og * 8) = pk;
  }
}

// ---------------- K4: layer-2 BN stats from y2t ----------------
__global__ void k_cstats(const u16* __restrict__ y2t, float* __restrict__ S2) {
  int t = threadIdx.x;
  int p0 = blockIdx.x * 128;
  int j = t & 15, pg = t >> 4;
  int c0 = j * 8;
  float s[8] = {0, 0, 0, 0, 0, 0, 0, 0}, q[8] = {0, 0, 0, 0, 0, 0, 0, 0};
  for (int i = 0; i < 8; ++i) {
    int p = p0 + i * 16 + pg;
    u16x8 v = *(const u16x8*)(y2t + (size_t)p * 128 + c0);
#pragma unroll
    for (int e = 0; e < 8; ++e) {
      float f = b2f(v[e]);
      s[e] += f;
      q[e] = fmaf(f, f, q[e]);
    }
  }
#pragma unroll
  for (int e = 0; e < 8; ++e) {
    s[e] += __shfl_xor(s[e], 16); s[e] += __shfl_xor(s[e], 32);
    q[e] += __shfl_xor(q[e], 16); q[e] += __shfl_xor(q[e], 32);
  }
  __shared__ float red[4][16][8][2];
  int lane = t & 63, wid = t >> 6;
  if (lane < 16) {
#pragma unroll
    for (int e = 0; e < 8; ++e) { red[wid][lane][e][0] = s[e]; red[wid][lane][e][1] = q[e]; }
  }
  __syncthreads();
  if (t < 128) {
    int jj = t >> 3, e = t & 7;
    float ss = 0.f, qq = 0.f;
    for (int w = 0; w < 4; ++w) { ss += red[w][jj][e][0]; qq += red[w][jj][e][1]; }
    atomicAdd(&S2[t], ss);
    atomicAdd(&S2[128 + t], qq);
  }
}

// ---------------- K5: finalize layer-2 BN scale/shift ----------------
__global__ void k_fin2(const float* __restrict__ S2, const float* __restrict__ g2,
                       const float* __restrict__ be2, float* __restrict__ SC2) {
  int o = threadIdx.x;  // 128
  float m = S2[o] / NSf;
  float v = S2[128 + o] / NSf - m * m;
  float sc = g2[o] * rsqrtf(v + EPS);
  SC2[o] = sc;
  SC2[128 + o] = be2[o] - m * sc;
}

// ---------------- K6: BN2+ReLU apply in place (y2t -> x2t) + colsum ----------
__global__ void k_bnapply(u16* __restrict__ y2t, const float* __restrict__ SC2,
                          float* __restrict__ CSv) {
  int t = threadIdx.x;
  int p0 = blockIdx.x * 128;
  int j = t & 15, pg = t >> 4;
  int c0 = j * 8;
  float sc[8], sh[8];
#pragma unroll
  for (int e = 0; e < 8; ++e) { sc[e] = SC2[c0 + e]; sh[e] = SC2[128 + c0 + e]; }
  float cs[8] = {0, 0, 0, 0, 0, 0, 0, 0};
  for (int i = 0; i < 8; ++i) {
    int p = p0 + i * 16 + pg;
    u16x8 v = *(u16x8*)(y2t + (size_t)p * 128 + c0);
    u16x8 r;
#pragma unroll
    for (int e = 0; e < 8; ++e) {
      float y = fmaxf(fmaf(sc[e], b2f(v[e]), sh[e]), 0.f);
      r[e] = f2b(y);
      cs[e] += b2f(r[e]);
    }
    *(u16x8*)(y2t + (size_t)p * 128 + c0) = r;
  }
#pragma unroll
  for (int e = 0; e < 8; ++e) { cs[e] += __shfl_xor(cs[e], 16); cs[e] += __shfl_xor(cs[e], 32); }
  __shared__ float red[4][16][8];
  int lane = t & 63, wid = t >> 6;
  if (lane < 16) {
#pragma unroll
    for (int e = 0; e < 8; ++e) red[wid][lane][e] = cs[e];
  }
  __syncthreads();
  if (t < 128) {
    int jj = t >> 3, e = t & 7;
    float ss = 0.f;
    for (int w = 0; w < 4; ++w) ss += red[w][jj][e];
    atomicAdd(&CSv[t], ss);
  }
}

// ---------------- K7: cast W3 to bf16 ----------------
__global__ void k_w3cast(const float* __restrict__ w3, u16* __restrict__ w3bf) {
  int id = blockIdx.x * 256 + threadIdx.x;
  if (id < 131072) w3bf[id] = f2b(w3[id]);
}

// ---------------- K8: Gram matrix G = sum x2 x2^T (MFMA) ----------------
__global__ __launch_bounds__(256) void k_gram(const u16* __restrict__ x2t,
                                              float* __restrict__ G) {
  __shared__ u16 T[128 * 128];  // [c][n] transposed, XOR-swizzled, 32KB
  int t = threadIdx.x;
  int g = blockIdx.x;           // 64 blocks: b = g>>3, points (g&7)*1024..+1024
  int b = g >> 3;
  int pbase = (g & 7) * 1024;
  int nn = t & 127, chalf = (t >> 7) * 64;
  int lane = t & 63, lr = lane & 15, lk = lane >> 4;
  int wid = __builtin_amdgcn_readfirstlane(t >> 6);
  int RB = (wid >> 1) * 64, CB = (wid & 1) * 64;
  f32x4 acc[4][4];
#pragma unroll
  for (int i = 0; i < 4; ++i)
#pragma unroll
    for (int jj = 0; jj < 4; ++jj) acc[i][jj] = (f32x4){0.f, 0.f, 0.f, 0.f};
  for (int st = 0; st < 8; ++st) {
    __syncthreads();
    const u16* srcp = x2t + ((size_t)(b * 8192 + pbase + st * 128 + nn)) * 128;
    for (int j8 = 0; j8 < 8; ++j8) {
      int c0 = chalf + j8 * 8;
      u16x8 v = *(const u16x8*)(srcp + c0);
#pragma unroll
      for (int e = 0; e < 8; ++e) {
        int c = c0 + e;
        int ba = (c << 8) | ((2 * nn) ^ ((c & 7) << 4));
        *(u16*)((char*)T + ba) = v[e];
      }
    }
    __syncthreads();
#pragma unroll
    for (int kk = 0; kk < 4; ++kk) {
      int cbs = (kk * 64 + lk * 16) ^ ((lr & 7) << 4);
      bf16x8 a[4], bb[4];
#pragma unroll
      for (int i = 0; i < 4; ++i)
        a[i] = *(const bf16x8*)((const char*)T + ((RB + i * 16 + lr) << 8) + cbs);
#pragma unroll
      for (int jj = 0; jj < 4; ++jj)
        bb[jj] = *(const bf16x8*)((const char*)T + ((CB + jj * 16 + lr) << 8) + cbs);
#pragma unroll
      for (int i = 0; i < 4; ++i)
#pragma unroll
        for (int jj = 0; jj < 4; ++jj)
          acc[i][jj] = __builtin_amdgcn_mfma_f32_16x16x32_bf16(a[i], bb[jj], acc[i][jj], 0, 0, 0);
    }
  }
#pragma unroll
  for (int i = 0; i < 4; ++i)
#pragma unroll
    for (int jj = 0; jj < 4; ++jj)
#pragma unroll
      for (int r = 0; r < 4; ++r) {
        int c = RB + i * 16 + lk * 4 + r;
        int c2 = CB + jj * 16 + lr;
        atomicAdd(&G[c * 128 + c2], acc[i][jj][r]);
      }
}

// ---------------- K9: conv3 MFMA + max-pool epilogue (y3 never stored) -------
__global__ __launch_bounds__(256) void k_conv3(const u16* __restrict__ x2t,
                                               const u16* __restrict__ w3bf,
                                               const float* __restrict__ b3,
                                               float* __restrict__ PMAXf) {
  __shared__ char sh[65536];  // W tile 32KB [o][k] + X tile 32KB [n][k], swizzled
  int bid = blockIdx.x;
  int lb = (bid & 7) * 512 + (bid >> 3);  // XCD-chunked swizzle (4096 = 8*512)
  int ob = lb & 7, nt = (lb >> 3) & 63, b = lb >> 9;
  int o0 = ob * 128, n0 = nt * 128;
  int t = threadIdx.x;
  int lane = t & 63, lr = lane & 15, lk = lane >> 4;
  int wid = __builtin_amdgcn_readfirstlane(t >> 6);
  // stage: per wave 8KB of W + 8KB of X, pre-swizzled global source
  for (int i = 0; i < 8; ++i) {
    int s = wid * 8192 + i * 1024 + lane * 16;
    int r = s >> 8, cb = s & 255;
    int scb = cb ^ ((r & 7) << 4);
    gl16((const char*)w3bf + (((size_t)(o0 + r)) << 8) + scb,
         sh + wid * 8192 + i * 1024);
    gl16((const char*)x2t + (size_t)b * 2097152 + (((size_t)(n0 + r)) << 8) + scb,
         sh + 32768 + wid * 8192 + i * 1024);
  }
  __syncthreads();
  int RB = (wid >> 1) * 64, CB = (wid & 1) * 64;
  f32x4 acc[4][4];
#pragma unroll
  for (int i = 0; i < 4; ++i)
#pragma unroll
    for (int j = 0; j < 4; ++j) acc[i][j] = (f32x4){0.f, 0.f, 0.f, 0.f};
#pragma unroll
  for (int kk = 0; kk < 4; ++kk) {
    int cbs = (kk * 64 + lk * 16) ^ ((lr & 7) << 4);
    bf16x8 a[4], bb[4];
#pragma unroll
    for (int i = 0; i < 4; ++i)
      a[i] = *(const bf16x8*)(sh + ((RB + i * 16 + lr) << 8) + cbs);
#pragma unroll
    for (int j = 0; j < 4; ++j)
      bb[j] = *(const bf16x8*)(sh + 32768 + ((CB + j * 16 + lr) << 8) + cbs);
#pragma unroll
    for (int i = 0; i < 4; ++i)
#pragma unroll
      for (int j = 0; j < 4; ++j)
        acc[i][j] = __builtin_amdgcn_mfma_f32_16x16x32_bf16(a[i], bb[j], acc[i][j], 0, 0, 0);
  }
  // epilogue: per-row max over this block's 128 cols -> atomicMax (g3>0)
#pragma unroll
  for (int i = 0; i < 4; ++i)
#pragma unroll
    for (int r = 0; r < 4; ++r) {
      float mx = fmaxf(fmaxf(acc[i][0][r], acc[i][1][r]), fmaxf(acc[i][2][r], acc[i][3][r]));
      mx = fmaxf(mx, __shfl_xor(mx, 1));
      mx = fmaxf(mx, __shfl_xor(mx, 2));
      mx = fmaxf(mx, __shfl_xor(mx, 4));
      mx = fmaxf(mx, __shfl_xor(mx, 8));
      if (lr == 0) {
        int o = o0 + RB + i * 16 + lk * 4 + r;
        atomicMax((unsigned*)&PMAXf[b * 1024 + o], fmap(mx + b3[o]));
      }
    }
}

// ---------------- K10: BN3 stats from colsum + Gram quadratic form ----------
__global__ void k_quad(const float* __restrict__ G, const float* __restrict__ CSv,
                       const float* __restrict__ w3, const float* __restrict__ b3,
                       float* __restrict__ S3) {
  int o = blockIdx.x, l = threadIdx.x;  // 64 threads
  __shared__ float wv[128];
  wv[l] = w3[o * 128 + l];
  wv[l + 64] = w3[o * 128 + 64 + l];
  __syncthreads();
  float h1 = 0.f, h2 = 0.f;
  const float* g1r = G + (2 * l) * 128;
  const float* g2r = G + (2 * l + 1) * 128;
  for (int k = 0; k < 128; ++k) {
    float w = wv[k];
    h1 = fmaf(g1r[k], w, h1);
    h2 = fmaf(g2r[k], w, h2);
  }
  float wa = wv[2 * l], wb = wv[2 * l + 1];
  float q = wa * h1 + wb * h2;
  float dw = wa * CSv[2 * l] + wb * CSv[2 * l + 1];
  for (int off = 32; off; off >>= 1) { q += __shfl_xor(q, off); dw += __shfl_xor(dw, off); }
  if (l == 0) {
    float bb = b3[o];
    S3[o] = dw + NSf * bb;
    S3[1024 + o] = q + 2.f * bb * dw + NSf * bb * bb;
  }
}

// ---------------- K11: finalize pool = relu(bn(max)) ----------------
__global__ void k_pool(const float* __restrict__ S3, const float* __restrict__ g3,
                       const float* __restrict__ be3, const float* __restrict__ PMAXf,
                       float* __restrict__ POOL) {
  int idx = blockIdx.x * 256 + threadIdx.x;  // b*1024+o
  int o = idx & 1023;
  float m = S3[o] / NSf;
  float v = S3[1024 + o] / NSf - m * m;
  float sc = g3[o] * rsqrtf(v + EPS);
  float sh = be3[o] - m * sc;
  float mx = funmap(((const unsigned*)PMAXf)[idx]);
  POOL[idx] = fmaxf(fmaf(sc, mx, sh), 0.f);
}

// ---------------- K12/K13: FC + BN(8) + ReLU ----------------
__global__ void k_fc(const float* __restrict__ xin, const float* __restrict__ w,
                     const float* __restrict__ bias, const float* __restrict__ g,
                     const float* __restrict__ be, float* __restrict__ out,
                     int K, int O) {
  int o = blockIdx.x, lane = threadIdx.x;  // 64 threads
  float yb[8] = {0.f, 0.f, 0.f, 0.f, 0.f, 0.f, 0.f, 0.f};
  for (int j = 0; j < K; j += 64) {
    float wv = w[(size_t)o * K + j + lane];
#pragma unroll
    for (int b = 0; b < 8; ++b) yb[b] = fmaf(wv, xin[b * K + j + lane], yb[b]);
  }
#pragma unroll
  for (int b = 0; b < 8; ++b)
    for (int off = 32; off; off >>= 1) yb[b] += __shfl_xor(yb[b], off);
  if (lane == 0) {
    float y[8];
    float m = 0.f;
#pragma unroll
    for (int b = 0; b < 8; ++b) { y[b] = yb[b] + bias[o]; m += y[b]; }
    m *= 0.125f;
    float v = 0.f;
#pragma unroll
    for (int b = 0; b < 8; ++b) { float d = y[b] - m; v = fmaf(d, d, v); }
    v *= 0.125f;
    float sc = g[o] * rsqrtf(v + EPS);
    float sh = be[o] - m * sc;
#pragma unroll
    for (int b = 0; b < 8; ++b) out[b * O + o] = fmaxf(fmaf(sc, y[b], sh), 0.f);
  }
}

// ---------------- K14: rot/trans heads ----------------
__global__ void k_rot(const float* __restrict__ x, const float* __restrict__ wr,
                      const float* __restrict__ br, const float* __restrict__ wt,
                      const float* __restrict__ bt, float* __restrict__ ROT,
                      float* __restrict__ TRANS) {
  int q = blockIdx.x;  // 96
  int b = q / 12, j = q % 12;
  int lane = threadIdx.x;
  float p = 0.f;
#pragma unroll
  for (int i = 0; i < 4; ++i) {
    int kk = i * 64 + lane;
    float w = (j < 9) ? wr[j * 256 + kk] : wt[(j - 9) * 256 + kk];
    p = fmaf(w, x[b * 256 + kk], p);
  }
  for (int off = 32; off; off >>= 1) p += __shfl_xor(p, off);
  if (lane == 0) {
    if (j < 9)
      ROT[b * 9 + j] = p + br[j] + ((j == 0 || j == 4 || j == 8) ? 1.f : 0.f);
    else
      TRANS[b * 3 + (j - 9)] = p + bt[j - 9];
  }
}

// ---------------- K15: apply transform + dist accumulation ----------------
__global__ void k_transform(const float* __restrict__ src, const float* __restrict__ tgt,
                            const float* __restrict__ ROT, const float* __restrict__ TRANS,
                            float* __restrict__ out, float* __restrict__ DIST) {
  int bx = blockIdx.x, t = threadIdx.x;
  int b = bx >> 5;
  int n = ((bx & 31) << 8) + t;
  float s0 = src[(b * 3 + 0) * 8192 + n];
  float s1 = src[(b * 3 + 1) * 8192 + n];
  float s2 = src[(b * 3 + 2) * 8192 + n];
  const float* R = ROT + b * 9;
  const float* T = TRANS + b * 3;
  float st[3];
#pragma unroll
  for (int c = 0; c < 3; ++c) {
    st[c] = fmaf(s0, R[0 * 3 + c], fmaf(s1, R[1 * 3 + c], fmaf(s2, R[2 * 3 + c], T[c])));
    out[1 + (b * 3 + c) * 8192 + n] = st[c];
  }
  float tg[3];
#pragma unroll
  for (int i = 0; i < 3; ++i) tg[i] = tgt[(b * 3 + i) * 8192 + n];
  float d[9];
#pragma unroll
  for (int i = 0; i < 3; ++i)
#pragma unroll
    for (int j = 0; j < 3; ++j) {
      float df = st[j] - tg[i];
      d[i * 3 + j] = df * df;
    }
#pragma unroll
  for (int k = 0; k < 9; ++k)
    for (int off = 32; off; off >>= 1) d[k] += __shfl_xor(d[k], off);
  if ((t & 63) == 0) {
#pragma unroll
    for (int k = 0; k < 9; ++k) atomicAdd(&DIST[b * 9 + k], d[k]);
  }
}

// ---------------- K16: loss ----------------
__global__ void k_loss(const float* __restrict__ DIST, float* __restrict__ out) {
  if (threadIdx.x == 0 && blockIdx.x == 0) {
    float acc = 0.f;
    for (int b = 0; b < 8; ++b) {
      const float* D = DIST + b * 9;
      for (int j = 0; j < 3; ++j)
        acc += fminf(D[j], fminf(D[3 + j], D[6 + j]));
      for (int i = 0; i < 3; ++i)
        acc += fminf(D[i * 3], fminf(D[i * 3 + 1], D[i * 3 + 2]));
    }
    out[0] = acc / 24.f;
  }
}

extern "C" void kernel_launch(void* const* d_in, const int* in_sizes, int n_in,
                              void* d_out, int out_size, void* d_ws, size_t ws_size,
                              hipStream_t stream) {
  const float* src = (const float*)d_in[0];
  const float* tgt = (const float*)d_in[1];
  const float* w1 = (const float*)d_in[2];
  const float* b1 = (const float*)d_in[3];
  const float* w2 = (const float*)d_in[4];
  const float* b2 = (const float*)d_in[5];
  const float* w3 = (const float*)d_in[6];
  const float* b3 = (const float*)d_in[7];
  const float* fw1 = (const float*)d_in[8];
  const float* fb1 = (const float*)d_in[9];
  const float* fw2 = (const float*)d_in[10];
  const float* fb2 = (const float*)d_in[11];
  const float* wr = (const float*)d_in[12];
  const float* br = (const float*)d_in[13];
  const float* wt = (const float*)d_in[14];
  const float* bt = (const float*)d_in[15];
  const float* g1 = (const float*)d_in[16];
  const float* be1 = (const float*)d_in[17];
  const float* g2 = (const float*)d_in[18];
  const float* be2 = (const float*)d_in[19];
  const float* g3 = (const float*)d_in[20];
  const float* be3 = (const float*)d_in[21];
  const float* g4 = (const float*)d_in[22];
  const float* be4 = (const float*)d_in[23];
  const float* g5 = (const float*)d_in[24];
  const float* be5 = (const float*)d_in[25];
  float* out = (float*)d_out;
  float* ws = (float*)d_ws;
  u16* y2t = (u16*)(ws + WS_Y2T);   // becomes x2t in place after k_bnapply
  u16* w3bf = (u16*)(ws + WS_W3BF);

  k_init<<<(WS_END - WS_G + 255) / 256, 256, 0, stream>>>(ws);
  k_stats_src<<<256, 256, 0, stream>>>(src, ws + WS_SRCM);
  k_fin1<<<1, 64, 0, stream>>>(ws + WS_SRCM, w1, b1, g1, be1, ws + WS_EFF1);
  k_conv2<<<256, 256, 0, stream>>>(src, ws + WS_EFF1, w2, b2, y2t);
  k_cstats<<<512, 256, 0, stream>>>(y2t, ws + WS_S2);
  k_fin2<<<1, 128, 0, stream>>>(ws + WS_S2, g2, be2, ws + WS_SC2);
  k_bnapply<<<512, 256, 0, stream>>>(y2t, ws + WS_SC2, ws + WS_CS);
  k_w3cast<<<512, 256, 0, stream>>>(w3, w3bf);
  k_gram<<<64, 256, 0, stream>>>(y2t, ws + WS_G);
  k_conv3<<<4096, 256, 0, stream>>>(y2t, w3bf, b3, ws + WS_PMAX);
  k_quad<<<1024, 64, 0, stream>>>(ws + WS_G, ws + WS_CS, w3, b3, ws + WS_S3);
  k_pool<<<32, 256, 0, stream>>>(ws + WS_S3, g3, be3, ws + WS_PMAX, ws + WS_POOL);
  k_fc<<<512, 64, 0, stream>>>(ws + WS_POOL, fw1, fb1, g4, be4, ws + WS_FC1, 1024, 512);
  k_fc<<<256, 64, 0, stream>>>(ws + WS_FC1, fw2, fb2, g5, be5, ws + WS_FC2, 512, 256);
  k_rot<<<96, 64, 0, stream>>>(ws + WS_FC2, wr, br, wt, bt, ws + WS_ROT, ws + WS_TRANS);
  k_transform<<<256, 256, 0, stream>>>(src, tgt, ws + WS_ROT, ws + WS_TRANS, out,
                                       ws + WS_DIST);
  k_loss<<<1, 64, 0, stream>>>(ws + WS_DIST, out);
}

// Round 3
// 185.638 us; speedup vs baseline: 4.2749x; 2.4267x over previous
//
#include <hip/hip_runtime.h>
#include <hip/hip_bf16.h>

#define EPS 1e-5f
#define NSf 65536.0f

typedef unsigned short u16;
typedef __attribute__((ext_vector_type(8))) unsigned short u16x8;
typedef __attribute__((ext_vector_type(4))) unsigned short u16x4;
typedef __attribute__((ext_vector_type(8))) short bf16x8;
typedef __attribute__((ext_vector_type(4))) float f32x4;

// ---------------- workspace layout (float offsets) ----------------
#define WS_Y2T   0                         // 8,388,608 bf16 = 4,194,304 floats (x2t)
#define WS_W3BF  4194304                   // 131072 bf16
#define WS_W2BF  4259840                   // 8192 bf16
#define WS_GP    4263936                   // 64 * 16384 f32 gram partials
#define WS_G     5312512                   // 16384 f32
#define WS_G1P   5328896                   // 256 * 5120 f32 x1-gram partials
#define WS_G1    6639616                   // 5120 f32 (rows 0..63 = G1, row 64 = cs1)
#define WS_SP    6644736                   // 64 * 12 src-moment partials
#define WS_EFF1  6645504                   // 256
#define WS_SC2   6645760                   // 256
#define WS_CS2S  6646016                   // 8 * 128 cs2 slots        <- cleared
#define WS_S3    6647040                   // 2048
#define WS_PMAX  6649088                   // 8192 mapped-uint         <- cleared
#define WS_POOL  6657280                   // 8192
#define WS_FC1   6665472                   // 4096
#define WS_FC2   6669568                   // 2048
#define WS_ROT   6671616                   // 96
#define WS_TRANS 6671712                   // 32
#define WS_DIST  6671744                   // 96                       <- cleared
#define WS_END   6671840

__device__ __forceinline__ unsigned fmap(float f) {
  unsigned u = __float_as_uint(f);
  return (u & 0x80000000u) ? ~u : (u | 0x80000000u);
}
__device__ __forceinline__ float funmap(unsigned u) {
  return __uint_as_float((u & 0x80000000u) ? (u ^ 0x80000000u) : ~u);
}
__device__ __forceinline__ u16 f2b(float f) {
  unsigned u = __float_as_uint(f);
  u += 0x7FFFu + ((u >> 16) & 1);
  return (u16)(u >> 16);
}
__device__ __forceinline__ float b2f(u16 h) { return __uint_as_float(((unsigned)h) << 16); }

__device__ __forceinline__ void gl16(const void* g, void* l) {
  __builtin_amdgcn_global_load_lds((const __attribute__((address_space(1))) unsigned*)g,
                                   (__attribute__((address_space(3))) unsigned*)l, 16, 0, 0);
}

// ---------------- K0: init the atomic accumulators only ----------------
__global__ void k_init(float* ws) {
  int idx = blockIdx.x * 256 + threadIdx.x;
  int total = WS_END - WS_CS2S;
  if (idx < total) ((unsigned*)ws)[WS_CS2S + idx] = 0u;  // PMAX mapped-0 == lowest
}

// ---------------- K1: cast w3, w2 to bf16 ----------------
__global__ void k_wcast(const float* __restrict__ w3, const float* __restrict__ w2,
                        u16* __restrict__ w3bf, u16* __restrict__ w2bf) {
  int id = blockIdx.x * 256 + threadIdx.x;
  if (id < 131072) w3bf[id] = f2b(w3[id]);
  else if (id < 139264) w2bf[id - 131072] = f2b(w2[id - 131072]);
}

// ---------------- K2: source moments -> per-block partials (no atomics) ------
__global__ void k_stats_src(const float* __restrict__ src, float* __restrict__ SP) {
  int t = threadIdx.x, bid = blockIdx.x;  // 64 blocks x 256
  float p[9] = {0, 0, 0, 0, 0, 0, 0, 0, 0};
  for (int it = 0; it < 4; ++it) {
    int id = bid * 1024 + it * 256 + t;
    int b = id >> 13, n = id & 8191;
    float s0 = src[(b * 3 + 0) * 8192 + n];
    float s1 = src[(b * 3 + 1) * 8192 + n];
    float s2 = src[(b * 3 + 2) * 8192 + n];
    p[0] += s0; p[1] += s1; p[2] += s2;
    p[3] = fmaf(s0, s0, p[3]); p[4] = fmaf(s0, s1, p[4]); p[5] = fmaf(s0, s2, p[5]);
    p[6] = fmaf(s1, s1, p[6]); p[7] = fmaf(s1, s2, p[7]); p[8] = fmaf(s2, s2, p[8]);
  }
#pragma unroll
  for (int i = 0; i < 9; ++i)
    for (int off = 32; off; off >>= 1) p[i] += __shfl_xor(p[i], off);
  __shared__ float red[4][9];
  int wv = t >> 6;
  if ((t & 63) == 0) {
#pragma unroll
    for (int i = 0; i < 9; ++i) red[wv][i] = p[i];
  }
  __syncthreads();
  if (t < 9) SP[bid * 12 + t] = red[0][t] + red[1][t] + red[2][t] + red[3][t];
}

// ---------------- K3: finalize layer-1 BN -> effective conv1 weights ----------
__global__ void k_fin1(const float* __restrict__ SP, const float* __restrict__ w1,
                       const float* __restrict__ b1, const float* __restrict__ g1,
                       const float* __restrict__ be1, float* __restrict__ eff) {
  __shared__ float M[9];
  int c = threadIdx.x;  // 64
  if (c < 9) {
    float s = 0.f;
    for (int b = 0; b < 64; ++b) s += SP[b * 12 + c];
    M[c] = s;
  }
  __syncthreads();
  float s0 = M[0], s1 = M[1], s2 = M[2];
  float ss00 = M[3], ss01 = M[4], ss02 = M[5], ss11 = M[6], ss12 = M[7], ss22 = M[8];
  float a0 = w1[c * 3], a1 = w1[c * 3 + 1], a2 = w1[c * 3 + 2], bb = b1[c];
  float dotS = a0 * s0 + a1 * s1 + a2 * s2;
  float sumY = dotS + NSf * bb;
  float sumY2 = a0 * a0 * ss00 + a1 * a1 * ss11 + a2 * a2 * ss22
              + 2.f * (a0 * a1 * ss01 + a0 * a2 * ss02 + a1 * a2 * ss12)
              + 2.f * bb * dotS + NSf * bb * bb;
  float m = sumY / NSf;
  float v = sumY2 / NSf - m * m;
  float sc = g1[c] * rsqrtf(v + EPS);
  float sh = be1[c] - m * sc;
  eff[c * 3 + 0] = sc * a0;
  eff[c * 3 + 1] = sc * a1;
  eff[c * 3 + 2] = sc * a2;
  eff[192 + c] = sc * bb + sh;
}

// ---------------- K4: x1 Gram G1e (80x64, row 64 = colsum) via MFMA ----------
__global__ __launch_bounds__(256) void k_x1stats(const float* __restrict__ src,
                                                 const float* __restrict__ eff,
                                                 float* __restrict__ G1P) {
  __shared__ char T[80 * 512];  // [row 0..79][256 p] bf16, swizzled (40KB)
  int t = threadIdx.x, bid = blockIdx.x;
  int lane = t & 63, lr = lane & 15, lk = lane >> 4;
  int w = __builtin_amdgcn_readfirstlane(t >> 6);
  int P = bid * 256 + t, b = P >> 13, n = P & 8191;
  float s0 = src[(b * 3 + 0) * 8192 + n];
  float s1 = src[(b * 3 + 1) * 8192 + n];
  float s2 = src[(b * 3 + 2) * 8192 + n];
#pragma unroll
  for (int c = 0; c < 64; ++c) {
    float v = fmaxf(fmaf(eff[c * 3], s0, fmaf(eff[c * 3 + 1], s1,
                    fmaf(eff[c * 3 + 2], s2, eff[192 + c]))), 0.f);
    *(u16*)(T + ((c << 9) | ((2 * t) ^ ((c & 7) << 4)))) = f2b(v);
  }
#pragma unroll
  for (int j = 0; j < 16; ++j) {
    int e = j * 256 + t;
    int row = 64 + (e >> 8), p = e & 255;
    *(u16*)(T + ((row << 9) | ((2 * p) ^ ((row & 7) << 4)))) = (row == 64) ? 0x3F80 : 0;
  }
  __syncthreads();
  f32x4 acc[5];
#pragma unroll
  for (int ri = 0; ri < 5; ++ri) acc[ri] = (f32x4){0.f, 0.f, 0.f, 0.f};
  int rb = w * 16 + lr;
#pragma unroll
  for (int ks = 0; ks < 8; ++ks) {
    bf16x8 bb = *(const bf16x8*)(T + ((rb << 9) | ((ks * 64 + lk * 16) ^ ((rb & 7) << 4))));
#pragma unroll
    for (int ri = 0; ri < 5; ++ri) {
      int ra = ri * 16 + lr;
      bf16x8 a = *(const bf16x8*)(T + ((ra << 9) | ((ks * 64 + lk * 16) ^ ((ra & 7) << 4))));
      acc[ri] = __builtin_amdgcn_mfma_f32_16x16x32_bf16(a, bb, acc[ri], 0, 0, 0);
    }
  }
  float* dst = G1P + bid * 5120;
#pragma unroll
  for (int ri = 0; ri < 5; ++ri)
#pragma unroll
    for (int r = 0; r < 4; ++r)
      dst[(ri * 16 + lk * 4 + r) * 64 + w * 16 + lr] = acc[ri][r];
}

// ---------------- K5: reduce G1 partials ----------------
__global__ void k_gred1(const float* __restrict__ G1P, float* __restrict__ G1) {
  int e = blockIdx.x * 256 + threadIdx.x;  // 20 blocks
  float s = 0.f;
  for (int p = 0; p < 256; ++p) s += G1P[p * 5120 + e];
  G1[e] = s;
}

// ---------------- K6: BN2 scale/shift from G1e ----------------
__global__ void k_fin2(const float* __restrict__ G1, const float* __restrict__ w2,
                       const float* __restrict__ b2, const float* __restrict__ g2,
                       const float* __restrict__ be2, float* __restrict__ SC2) {
  int o = blockIdx.x, l = threadIdx.x;  // 128 blocks x 64
  __shared__ float wv[64];
  wv[l] = w2[o * 64 + l];
  __syncthreads();
  float h = 0.f;
  const float* gr = G1 + l * 64;
  for (int k = 0; k < 64; ++k) h = fmaf(gr[k], wv[k], h);
  float q = wv[l] * h;
  float dw = wv[l] * G1[4096 + l];  // cs1 row
  for (int off = 32; off; off >>= 1) { q += __shfl_xor(q, off); dw += __shfl_xor(dw, off); }
  if (l == 0) {
    float bb = b2[o];
    float sumY = dw + NSf * bb;
    float sumY2 = q + 2.f * bb * dw + NSf * bb * bb;
    float m = sumY / NSf;
    float v = sumY2 / NSf - m * m;
    float sc = g2[o] * rsqrtf(v + EPS);
    float sh = be2[o] - m * sc;
    SC2[o] = sc;
    SC2[128 + o] = sc * bb + sh;  // fold conv bias into shift
  }
}

// ---------------- K7: conv2 MFMA + BN2 + ReLU -> x2t bf16 + cs2 slots --------
__global__ __launch_bounds__(256) void k_conv2(const float* __restrict__ src,
                                               const float* __restrict__ eff,
                                               const u16* __restrict__ w2bf,
                                               const float* __restrict__ SC2,
                                               u16* __restrict__ y2t,
                                               float* __restrict__ CS2S) {
  __shared__ char WT[16384];  // W2 [128o][64c] bf16 swizzled
  __shared__ char XT[32768];  // x1 [256p][64c] bf16 swizzled
  int t = threadIdx.x, bid = blockIdx.x;
  int lane = t & 63, lr = lane & 15, lk = lane >> 4;
  int w = __builtin_amdgcn_readfirstlane(t >> 6);
#pragma unroll
  for (int i = 0; i < 4; ++i) {
    int s = i * 4096 + t * 16;
    int o = s >> 7, cb = s & 127;
    gl16((const char*)w2bf + ((o << 7) | (cb ^ ((o & 7) << 4))), WT + s);
  }
  int P = bid * 256 + t, b = P >> 13, n = P & 8191;
  float s0 = src[(b * 3 + 0) * 8192 + n];
  float s1 = src[(b * 3 + 1) * 8192 + n];
  float s2 = src[(b * 3 + 2) * 8192 + n];
#pragma unroll
  for (int i = 0; i < 8; ++i) {
    u16x8 pk;
#pragma unroll
    for (int e = 0; e < 8; ++e) {
      int c = i * 8 + e;
      pk[e] = f2b(fmaxf(fmaf(eff[c * 3], s0, fmaf(eff[c * 3 + 1], s1,
                        fmaf(eff[c * 3 + 2], s2, eff[192 + c]))), 0.f));
    }
    *(u16x8*)(XT + ((t << 7) | ((i * 16) ^ ((t & 7) << 4)))) = pk;
  }
  __syncthreads();
  int o0w = (w & 1) * 64, p0w = (w >> 1) * 128;
  f32x4 acc[4][8];
#pragma unroll
  for (int i = 0; i < 4; ++i)
#pragma unroll
    for (int j = 0; j < 8; ++j) acc[i][j] = (f32x4){0.f, 0.f, 0.f, 0.f};
#pragma unroll
  for (int kk = 0; kk < 2; ++kk) {
    bf16x8 a[4], bb[8];
#pragma unroll
    for (int i = 0; i < 4; ++i) {
      int row = o0w + i * 16 + lr;
      a[i] = *(const bf16x8*)(WT + ((row << 7) | ((kk * 64 + lk * 16) ^ ((row & 7) << 4))));
    }
#pragma unroll
    for (int j = 0; j < 8; ++j) {
      int prow = p0w + j * 16 + lr;
      bb[j] = *(const bf16x8*)(XT + ((prow << 7) | ((kk * 64 + lk * 16) ^ ((prow & 7) << 4))));
    }
#pragma unroll
    for (int i = 0; i < 4; ++i)
#pragma unroll
      for (int j = 0; j < 8; ++j)
        acc[i][j] = __builtin_amdgcn_mfma_f32_16x16x32_bf16(a[i], bb[j], acc[i][j], 0, 0, 0);
  }
  float csum[4][4];
#pragma unroll
  for (int i = 0; i < 4; ++i) {
    int ob = o0w + i * 16 + lk * 4;
    float4 sc4 = *(const float4*)&SC2[ob];
    float4 sh4 = *(const float4*)&SC2[128 + ob];
    csum[i][0] = csum[i][1] = csum[i][2] = csum[i][3] = 0.f;
#pragma unroll
    for (int j = 0; j < 8; ++j) {
      int p = p0w + j * 16 + lr;
      u16x4 pk;
      float v0 = fmaxf(fmaf(sc4.x, acc[i][j][0], sh4.x), 0.f); csum[i][0] += v0; pk[0] = f2b(v0);
      float v1 = fmaxf(fmaf(sc4.y, acc[i][j][1], sh4.y), 0.f); csum[i][1] += v1; pk[1] = f2b(v1);
      float v2 = fmaxf(fmaf(sc4.z, acc[i][j][2], sh4.z), 0.f); csum[i][2] += v2; pk[2] = f2b(v2);
      float v3 = fmaxf(fmaf(sc4.w, acc[i][j][3], sh4.w), 0.f); csum[i][3] += v3; pk[3] = f2b(v3);
      *(u16x4*)(y2t + (size_t)(bid * 256 + p) * 128 + ob) = pk;
    }
  }
#pragma unroll
  for (int i = 0; i < 4; ++i)
#pragma unroll
    for (int r = 0; r < 4; ++r) {
      float v = csum[i][r];
      v += __shfl_xor(v, 1); v += __shfl_xor(v, 2);
      v += __shfl_xor(v, 4); v += __shfl_xor(v, 8);
      if (lr == 0) atomicAdd(&CS2S[(bid & 7) * 128 + o0w + i * 16 + lk * 4 + r], v);
    }
}

// ---------------- K8: x2 Gram partials (no atomics) ----------------
__global__ __launch_bounds__(256) void k_gram(const u16* __restrict__ x2t,
                                              float* __restrict__ GP) {
  __shared__ u16 T[128 * 128];  // [c][n] transposed, swizzled, 32KB
  int t = threadIdx.x;
  int g = blockIdx.x;  // 64 blocks
  int b = g >> 3;
  int pbase = (g & 7) * 1024;
  int nn = t & 127, chalf = (t >> 7) * 64;
  int lane = t & 63, lr = lane & 15, lk = lane >> 4;
  int wid = __builtin_amdgcn_readfirstlane(t >> 6);
  int RB = (wid >> 1) * 64, CB = (wid & 1) * 64;
  f32x4 acc[4][4];
#pragma unroll
  for (int i = 0; i < 4; ++i)
#pragma unroll
    for (int jj = 0; jj < 4; ++jj) acc[i][jj] = (f32x4){0.f, 0.f, 0.f, 0.f};
  for (int st = 0; st < 8; ++st) {
    __syncthreads();
    const u16* srcp = x2t + ((size_t)(b * 8192 + pbase + st * 128 + nn)) * 128;
    for (int j8 = 0; j8 < 8; ++j8) {
      int c0 = chalf + j8 * 8;
      u16x8 v = *(const u16x8*)(srcp + c0);
#pragma unroll
      for (int e = 0; e < 8; ++e) {
        int c = c0 + e;
        int ba = (c << 8) | ((2 * nn) ^ ((c & 7) << 4));
        *(u16*)((char*)T + ba) = v[e];
      }
    }
    __syncthreads();
#pragma unroll
    for (int kk = 0; kk < 4; ++kk) {
      int cbs = (kk * 64 + lk * 16) ^ ((lr & 7) << 4);
      bf16x8 a[4], bb[4];
#pragma unroll
      for (int i = 0; i < 4; ++i)
        a[i] = *(const bf16x8*)((const char*)T + ((RB + i * 16 + lr) << 8) + cbs);
#pragma unroll
      for (int jj = 0; jj < 4; ++jj)
        bb[jj] = *(const bf16x8*)((const char*)T + ((CB + jj * 16 + lr) << 8) + cbs);
#pragma unroll
      for (int i = 0; i < 4; ++i)
#pragma unroll
        for (int jj = 0; jj < 4; ++jj)
          acc[i][jj] = __builtin_amdgcn_mfma_f32_16x16x32_bf16(a[i], bb[jj], acc[i][jj], 0, 0, 0);
    }
  }
  float* dst = GP + g * 16384;
#pragma unroll
  for (int i = 0; i < 4; ++i)
#pragma unroll
    for (int jj = 0; jj < 4; ++jj)
#pragma unroll
      for (int r = 0; r < 4; ++r)
        dst[(RB + i * 16 + lk * 4 + r) * 128 + CB + jj * 16 + lr] = acc[i][jj][r];
}

// ---------------- K9: reduce Gram partials ----------------
__global__ void k_gred(const float* __restrict__ GP, float* __restrict__ G) {
  int e = blockIdx.x * 256 + threadIdx.x;  // 64 blocks
  float s = 0.f;
  for (int p = 0; p < 64; ++p) s += GP[p * 16384 + e];
  G[e] = s;
}

// ---------------- K10: conv3 MFMA + max-pool epilogue ----------------
__global__ __launch_bounds__(256) void k_conv3(const u16* __restrict__ x2t,
                                               const u16* __restrict__ w3bf,
                                               const float* __restrict__ b3,
                                               float* __restrict__ PMAXf) {
  __shared__ char sh[65536];  // W tile 32KB + X tile 32KB, swizzled
  int bid = blockIdx.x;
  int lb = (bid & 7) * 512 + (bid >> 3);  // XCD-chunked swizzle
  int ob = lb & 7, nt = (lb >> 3) & 63, b = lb >> 9;
  int o0 = ob * 128, n0 = nt * 128;
  int t = threadIdx.x;
  int lane = t & 63, lr = lane & 15, lk = lane >> 4;
  int wid = __builtin_amdgcn_readfirstlane(t >> 6);
  for (int i = 0; i < 8; ++i) {
    int s = wid * 8192 + i * 1024 + lane * 16;
    int r = s >> 8, cb = s & 255;
    int scb = cb ^ ((r & 7) << 4);
    gl16((const char*)w3bf + (((size_t)(o0 + r)) << 8) + scb,
         sh + wid * 8192 + i * 1024);
    gl16((const char*)x2t + (size_t)b * 2097152 + (((size_t)(n0 + r)) << 8) + scb,
         sh + 32768 + wid * 8192 + i * 1024);
  }
  __syncthreads();
  int RB = (wid >> 1) * 64, CB = (wid & 1) * 64;
  f32x4 acc[4][4];
#pragma unroll
  for (int i = 0; i < 4; ++i)
#pragma unroll
    for (int j = 0; j < 4; ++j) acc[i][j] = (f32x4){0.f, 0.f, 0.f, 0.f};
#pragma unroll
  for (int kk = 0; kk < 4; ++kk) {
    int cbs = (kk * 64 + lk * 16) ^ ((lr & 7) << 4);
    bf16x8 a[4], bb[4];
#pragma unroll
    for (int i = 0; i < 4; ++i)
      a[i] = *(const bf16x8*)(sh + ((RB + i * 16 + lr) << 8) + cbs);
#pragma unroll
    for (int j = 0; j < 4; ++j)
      bb[j] = *(const bf16x8*)(sh + 32768 + ((CB + j * 16 + lr) << 8) + cbs);
#pragma unroll
    for (int i = 0; i < 4; ++i)
#pragma unroll
      for (int j = 0; j < 4; ++j)
        acc[i][j] = __builtin_amdgcn_mfma_f32_16x16x32_bf16(a[i], bb[j], acc[i][j], 0, 0, 0);
  }
#pragma unroll
  for (int i = 0; i < 4; ++i)
#pragma unroll
    for (int r = 0; r < 4; ++r) {
      float mx = fmaxf(fmaxf(acc[i][0][r], acc[i][1][r]), fmaxf(acc[i][2][r], acc[i][3][r]));
      mx = fmaxf(mx, __shfl_xor(mx, 1));
      mx = fmaxf(mx, __shfl_xor(mx, 2));
      mx = fmaxf(mx, __shfl_xor(mx, 4));
      mx = fmaxf(mx, __shfl_xor(mx, 8));
      if (lr == 0) {
        int o = o0 + RB + i * 16 + lk * 4 + r;
        atomicMax((unsigned*)&PMAXf[b * 1024 + o], fmap(mx + b3[o]));
      }
    }
}

// ---------------- K11: BN3 stats from cs2 + Gram quadratic form ----------
__global__ void k_quad(const float* __restrict__ G, const float* __restrict__ CS2S,
                       const float* __restrict__ w3, const float* __restrict__ b3,
                       float* __restrict__ S3) {
  int o = blockIdx.x, l = threadIdx.x;  // 1024 x 64
  __shared__ float wv[128];
  wv[l] = w3[o * 128 + l];
  wv[l + 64] = w3[o * 128 + 64 + l];
  __syncthreads();
  float csA = 0.f, csB = 0.f;
#pragma unroll
  for (int s = 0; s < 8; ++s) { csA += CS2S[s * 128 + 2 * l]; csB += CS2S[s * 128 + 2 * l + 1]; }
  float h1 = 0.f, h2 = 0.f;
  const float* g1r = G + (2 * l) * 128;
  const float* g2r = G + (2 * l + 1) * 128;
  for (int k = 0; k < 128; ++k) {
    float w = wv[k];
    h1 = fmaf(g1r[k], w, h1);
    h2 = fmaf(g2r[k], w, h2);
  }
  float wa = wv[2 * l], wb = wv[2 * l + 1];
  float q = wa * h1 + wb * h2;
  float dw = wa * csA + wb * csB;
  for (int off = 32; off; off >>= 1) { q += __shfl_xor(q, off); dw += __shfl_xor(dw, off); }
  if (l == 0) {
    float bb = b3[o];
    S3[o] = dw + NSf * bb;
    S3[1024 + o] = q + 2.f * bb * dw + NSf * bb * bb;
  }
}

// ---------------- K12: finalize pool = relu(bn(max)) ----------------
__global__ void k_pool(const float* __restrict__ S3, const float* __restrict__ g3,
                       const float* __restrict__ be3, const float* __restrict__ PMAXf,
                       float* __restrict__ POOL) {
  int idx = blockIdx.x * 256 + threadIdx.x;
  int o = idx & 1023;
  float m = S3[o] / NSf;
  float v = S3[1024 + o] / NSf - m * m;
  float sc = g3[o] * rsqrtf(v + EPS);
  float sh = be3[o] - m * sc;
  float mx = funmap(((const unsigned*)PMAXf)[idx]);
  POOL[idx] = fmaxf(fmaf(sc, mx, sh), 0.f);
}

// ---------------- K13/K14: FC + BN(8) + ReLU ----------------
__global__ void k_fc(const float* __restrict__ xin, const float* __restrict__ w,
                     const float* __restrict__ bias, const float* __restrict__ g,
                     const float* __restrict__ be, float* __restrict__ out,
                     int K, int O) {
  int o = blockIdx.x, lane = threadIdx.x;  // 64 threads
  float yb[8] = {0.f, 0.f, 0.f, 0.f, 0.f, 0.f, 0.f, 0.f};
  for (int j = 0; j < K; j += 64) {
    float wv = w[(size_t)o * K + j + lane];
#pragma unroll
    for (int b = 0; b < 8; ++b) yb[b] = fmaf(wv, xin[b * K + j + lane], yb[b]);
  }
#pragma unroll
  for (int b = 0; b < 8; ++b)
    for (int off = 32; off; off >>= 1) yb[b] += __shfl_xor(yb[b], off);
  if (lane == 0) {
    float y[8];
    float m = 0.f;
#pragma unroll
    for (int b = 0; b < 8; ++b) { y[b] = yb[b] + bias[o]; m += y[b]; }
    m *= 0.125f;
    float v = 0.f;
#pragma unroll
    for (int b = 0; b < 8; ++b) { float d = y[b] - m; v = fmaf(d, d, v); }
    v *= 0.125f;
    float sc = g[o] * rsqrtf(v + EPS);
    float sh = be[o] - m * sc;
#pragma unroll
    for (int b = 0; b < 8; ++b) out[b * O + o] = fmaxf(fmaf(sc, y[b], sh), 0.f);
  }
}

// ---------------- K15: rot/trans heads ----------------
__global__ void k_rot(const float* __restrict__ x, const float* __restrict__ wr,
                      const float* __restrict__ br, const float* __restrict__ wt,
                      const float* __restrict__ bt, float* __restrict__ ROT,
                      float* __restrict__ TRANS) {
  int q = blockIdx.x;  // 96
  int b = q / 12, j = q % 12;
  int lane = threadIdx.x;
  float p = 0.f;
#pragma unroll
  for (int i = 0; i < 4; ++i) {
    int kk = i * 64 + lane;
    float w = (j < 9) ? wr[j * 256 + kk] : wt[(j - 9) * 256 + kk];
    p = fmaf(w, x[b * 256 + kk], p);
  }
  for (int off = 32; off; off >>= 1) p += __shfl_xor(p, off);
  if (lane == 0) {
    if (j < 9)
      ROT[b * 9 + j] = p + br[j] + ((j == 0 || j == 4 || j == 8) ? 1.f : 0.f);
    else
      TRANS[b * 3 + (j - 9)] = p + bt[j - 9];
  }
}

// ---------------- K16: apply transform + dist (block-reduced atomics) --------
__global__ void k_transform(const float* __restrict__ src, const float* __restrict__ tgt,
                            const float* __restrict__ ROT, const float* __restrict__ TRANS,
                            float* __restrict__ out, float* __restrict__ DIST) {
  int bx = blockIdx.x, t = threadIdx.x;
  int b = bx >> 5;
  int n = ((bx & 31) << 8) + t;
  float s0 = src[(b * 3 + 0) * 8192 + n];
  float s1 = src[(b * 3 + 1) * 8192 + n];
  float s2 = src[(b * 3 + 2) * 8192 + n];
  const float* R = ROT + b * 9;
  const float* T = TRANS + b * 3;
  float st[3];
#pragma unroll
  for (int c = 0; c < 3; ++c) {
    st[c] = fmaf(s0, R[0 * 3 + c], fmaf(s1, R[1 * 3 + c], fmaf(s2, R[2 * 3 + c], T[c])));
    out[1 + (b * 3 + c) * 8192 + n] = st[c];
  }
  float tg[3];
#pragma unroll
  for (int i = 0; i < 3; ++i) tg[i] = tgt[(b * 3 + i) * 8192 + n];
  float d[9];
#pragma unroll
  for (int i = 0; i < 3; ++i)
#pragma unroll
    for (int j = 0; j < 3; ++j) {
      float df = st[j] - tg[i];
      d[i * 3 + j] = df * df;
    }
#pragma unroll
  for (int k = 0; k < 9; ++k)
    for (int off = 32; off; off >>= 1) d[k] += __shfl_xor(d[k], off);
  __shared__ float red[4][9];
  int wv = t >> 6;
  if ((t & 63) == 0) {
#pragma unroll
    for (int k = 0; k < 9; ++k) red[wv][k] = d[k];
  }
  __syncthreads();
  if (t < 9) {
    float s = red[0][t] + red[1][t] + red[2][t] + red[3][t];
    atomicAdd(&DIST[b * 9 + t], s);
  }
}

// ---------------- K17: loss ----------------
__global__ void k_loss(const float* __restrict__ DIST, float* __restrict__ out) {
  if (threadIdx.x == 0 && blockIdx.x == 0) {
    float acc = 0.f;
    for (int b = 0; b < 8; ++b) {
      const float* D = DIST + b * 9;
      for (int j = 0; j < 3; ++j)
        acc += fminf(D[j], fminf(D[3 + j], D[6 + j]));
      for (int i = 0; i < 3; ++i)
        acc += fminf(D[i * 3], fminf(D[i * 3 + 1], D[i * 3 + 2]));
    }
    out[0] = acc / 24.f;
  }
}

extern "C" void kernel_launch(void* const* d_in, const int* in_sizes, int n_in,
                              void* d_out, int out_size, void* d_ws, size_t ws_size,
                              hipStream_t stream) {
  const float* src = (const float*)d_in[0];
  const float* tgt = (const float*)d_in[1];
  const float* w1 = (const float*)d_in[2];
  const float* b1 = (const float*)d_in[3];
  const float* w2 = (const float*)d_in[4];
  const float* b2 = (const float*)d_in[5];
  const float* w3 = (const float*)d_in[6];
  const float* b3 = (const float*)d_in[7];
  const float* fw1 = (const float*)d_in[8];
  const float* fb1 = (const float*)d_in[9];
  const float* fw2 = (const float*)d_in[10];
  const float* fb2 = (const float*)d_in[11];
  const float* wr = (const float*)d_in[12];
  const float* br = (const float*)d_in[13];
  const float* wt = (const float*)d_in[14];
  const float* bt = (const float*)d_in[15];
  const float* g1 = (const float*)d_in[16];
  const float* be1 = (const float*)d_in[17];
  const float* g2 = (const float*)d_in[18];
  const float* be2 = (const float*)d_in[19];
  const float* g3 = (const float*)d_in[20];
  const float* be3 = (const float*)d_in[21];
  const float* g4 = (const float*)d_in[22];
  const float* be4 = (const float*)d_in[23];
  const float* g5 = (const float*)d_in[24];
  const float* be5 = (const float*)d_in[25];
  float* out = (float*)d_out;
  float* ws = (float*)d_ws;
  u16* y2t = (u16*)(ws + WS_Y2T);
  u16* w3bf = (u16*)(ws + WS_W3BF);
  u16* w2bf = (u16*)(ws + WS_W2BF);

  k_init<<<(WS_END - WS_CS2S + 255) / 256, 256, 0, stream>>>(ws);
  k_wcast<<<544, 256, 0, stream>>>(w3, w2, w3bf, w2bf);
  k_stats_src<<<64, 256, 0, stream>>>(src, ws + WS_SP);
  k_fin1<<<1, 64, 0, stream>>>(ws + WS_SP, w1, b1, g1, be1, ws + WS_EFF1);
  k_x1stats<<<256, 256, 0, stream>>>(src, ws + WS_EFF1, ws + WS_G1P);
  k_gred1<<<20, 256, 0, stream>>>(ws + WS_G1P, ws + WS_G1);
  k_fin2<<<128, 64, 0, stream>>>(ws + WS_G1, w2, b2, g2, be2, ws + WS_SC2);
  k_conv2<<<256, 256, 0, stream>>>(src, ws + WS_EFF1, w2bf, ws + WS_SC2, y2t,
                                   ws + WS_CS2S);
  k_gram<<<64, 256, 0, stream>>>(y2t, ws + WS_GP);
  k_gred<<<64, 256, 0, stream>>>(ws + WS_GP, ws + WS_G);
  k_conv3<<<4096, 256, 0, stream>>>(y2t, w3bf, b3, ws + WS_PMAX);
  k_quad<<<1024, 64, 0, stream>>>(ws + WS_G, ws + WS_CS2S, w3, b3, ws + WS_S3);
  k_pool<<<32, 256, 0, stream>>>(ws + WS_S3, g3, be3, ws + WS_PMAX, ws + WS_POOL);
  k_fc<<<512, 64, 0, stream>>>(ws + WS_POOL, fw1, fb1, g4, be4, ws + WS_FC1, 1024, 512);
  k_fc<<<256, 64, 0, stream>>>(ws + WS_FC1, fw2, fb2, g5, be5, ws + WS_FC2, 512, 256);
  k_rot<<<96, 64, 0, stream>>>(ws + WS_FC2, wr, br, wt, bt, ws + WS_ROT, ws + WS_TRANS);
  k_transform<<<256, 256, 0, stream>>>(src, tgt, ws + WS_ROT, ws + WS_TRANS, out,
                                       ws + WS_DIST);
  k_loss<<<1, 64, 0, stream>>>(ws + WS_DIST, out);
}

// Round 4
// 96.210 us; speedup vs baseline: 8.2485x; 1.9295x over previous
//
#include <hip/hip_runtime.h>
#include <hip/hip_bf16.h>

#define EPS 1e-5f
#define NSf 65536.0f

typedef unsigned short u16;
typedef __attribute__((ext_vector_type(8))) unsigned short u16x8;
typedef __attribute__((ext_vector_type(4))) unsigned short u16x4;
typedef __attribute__((ext_vector_type(8))) short bf16x8;
typedef __attribute__((ext_vector_type(4))) float f32x4;

// ---------------- workspace layout (float offsets) ----------------
#define WS_Y2T   0                         // 8,388,608 bf16 = 4,194,304 floats (x2t)
#define WS_W3BF  4194304                   // 131072 bf16
#define WS_W2BF  4259840                   // 8192 bf16
#define WS_G1P   4263936                   // 256 * 5120 f32 x1-gram partials
#define WS_G1    5574656                   // 5120 (rows 0..63 = G1, row 64 = cs1)
#define WS_SP    5579776                   // 64 * 12 src-moment partials
#define WS_EFF1  5580544                   // 256
#define WS_SC2   5580800                   // 256
#define WS_SUMP  5581056                   // 16*8*1024 conv3 sum partials
#define WS_SQP   5712128                   // 16*8*1024 sq partials
#define WS_MAXP  5843200                   // 16*8*1024 max partials
#define WS_POOL  5974272                   // 8192
#define WS_FC1   5982464                   // 4096
#define WS_FC2   5986560                   // 2048
#define WS_ROT   5988608                   // 96
#define WS_TRANS 5988704                   // 32
#define WS_DIST  5988736                   // 96   <- cleared in k_prep
#define WS_END   5988832

__device__ __forceinline__ u16 f2b(float f) {
  unsigned u = __float_as_uint(f);
  u += 0x7FFFu + ((u >> 16) & 1);
  return (u16)(u >> 16);
}
__device__ __forceinline__ float b2f(u16 h) { return __uint_as_float(((unsigned)h) << 16); }

__device__ __forceinline__ void gl16(const void* g, void* l) {
  __builtin_amdgcn_global_load_lds((const __attribute__((address_space(1))) unsigned*)g,
                                   (__attribute__((address_space(3))) unsigned*)l, 16, 0, 0);
}

// ---------------- K0: prep = wcast (544 blocks) + src moments (64) + DIST clear
__global__ void k_prep(const float* __restrict__ w3, const float* __restrict__ w2,
                       const float* __restrict__ src, u16* __restrict__ w3bf,
                       u16* __restrict__ w2bf, float* __restrict__ SP,
                       float* __restrict__ DIST) {
  int bid = blockIdx.x, t = threadIdx.x;
  if (bid < 544) {
    int id = bid * 256 + t;
    if (id < 131072) w3bf[id] = f2b(w3[id]);
    else w2bf[id - 131072] = f2b(w2[id - 131072]);
    return;
  }
  int sb = bid - 544;  // 0..63
  if (sb == 0 && t < 96) DIST[t] = 0.f;
  float p[9] = {0, 0, 0, 0, 0, 0, 0, 0, 0};
  for (int it = 0; it < 4; ++it) {
    int id = sb * 1024 + it * 256 + t;
    int b = id >> 13, n = id & 8191;
    float s0 = src[(b * 3 + 0) * 8192 + n];
    float s1 = src[(b * 3 + 1) * 8192 + n];
    float s2 = src[(b * 3 + 2) * 8192 + n];
    p[0] += s0; p[1] += s1; p[2] += s2;
    p[3] = fmaf(s0, s0, p[3]); p[4] = fmaf(s0, s1, p[4]); p[5] = fmaf(s0, s2, p[5]);
    p[6] = fmaf(s1, s1, p[6]); p[7] = fmaf(s1, s2, p[7]); p[8] = fmaf(s2, s2, p[8]);
  }
#pragma unroll
  for (int i = 0; i < 9; ++i)
    for (int off = 32; off; off >>= 1) p[i] += __shfl_xor(p[i], off);
  __shared__ float red[4][9];
  int wv = t >> 6;
  if ((t & 63) == 0) {
#pragma unroll
    for (int i = 0; i < 9; ++i) red[wv][i] = p[i];
  }
  __syncthreads();
  if (t < 9) SP[sb * 12 + t] = red[0][t] + red[1][t] + red[2][t] + red[3][t];
}

// ---------------- K1: finalize layer-1 BN -> effective conv1 weights ----------
__global__ void k_fin1(const float* __restrict__ SP, const float* __restrict__ w1,
                       const float* __restrict__ b1, const float* __restrict__ g1,
                       const float* __restrict__ be1, float* __restrict__ eff) {
  __shared__ float M[9];
  int c = threadIdx.x;  // 64
  if (c < 9) {
    float s = 0.f;
    for (int b = 0; b < 64; ++b) s += SP[b * 12 + c];
    M[c] = s;
  }
  __syncthreads();
  float s0 = M[0], s1 = M[1], s2 = M[2];
  float ss00 = M[3], ss01 = M[4], ss02 = M[5], ss11 = M[6], ss12 = M[7], ss22 = M[8];
  float a0 = w1[c * 3], a1 = w1[c * 3 + 1], a2 = w1[c * 3 + 2], bb = b1[c];
  float dotS = a0 * s0 + a1 * s1 + a2 * s2;
  float sumY = dotS + NSf * bb;
  float sumY2 = a0 * a0 * ss00 + a1 * a1 * ss11 + a2 * a2 * ss22
              + 2.f * (a0 * a1 * ss01 + a0 * a2 * ss02 + a1 * a2 * ss12)
              + 2.f * bb * dotS + NSf * bb * bb;
  float m = sumY / NSf;
  float v = sumY2 / NSf - m * m;
  float sc = g1[c] * rsqrtf(v + EPS);
  float sh = be1[c] - m * sc;
  eff[c * 3 + 0] = sc * a0;
  eff[c * 3 + 1] = sc * a1;
  eff[c * 3 + 2] = sc * a2;
  eff[192 + c] = sc * bb + sh;
}

// ---------------- K2: x1 Gram G1e (80x64, row 64 = colsum) via MFMA ----------
__global__ __launch_bounds__(256) void k_x1stats(const float* __restrict__ src,
                                                 const float* __restrict__ eff,
                                                 float* __restrict__ G1P) {
  __shared__ char T[80 * 512];  // [row 0..79][256 p] bf16, swizzled (40KB)
  int t = threadIdx.x, bid = blockIdx.x;
  int lane = t & 63, lr = lane & 15, lk = lane >> 4;
  int w = __builtin_amdgcn_readfirstlane(t >> 6);
  int P = bid * 256 + t, b = P >> 13, n = P & 8191;
  float s0 = src[(b * 3 + 0) * 8192 + n];
  float s1 = src[(b * 3 + 1) * 8192 + n];
  float s2 = src[(b * 3 + 2) * 8192 + n];
#pragma unroll
  for (int c = 0; c < 64; ++c) {
    float v = fmaxf(fmaf(eff[c * 3], s0, fmaf(eff[c * 3 + 1], s1,
                    fmaf(eff[c * 3 + 2], s2, eff[192 + c]))), 0.f);
    *(u16*)(T + ((c << 9) | ((2 * t) ^ ((c & 7) << 4)))) = f2b(v);
  }
#pragma unroll
  for (int j = 0; j < 16; ++j) {
    int e = j * 256 + t;
    int row = 64 + (e >> 8), p = e & 255;
    *(u16*)(T + ((row << 9) | ((2 * p) ^ ((row & 7) << 4)))) = (row == 64) ? 0x3F80 : 0;
  }
  __syncthreads();
  f32x4 acc[5];
#pragma unroll
  for (int ri = 0; ri < 5; ++ri) acc[ri] = (f32x4){0.f, 0.f, 0.f, 0.f};
  int rb = w * 16 + lr;
#pragma unroll
  for (int ks = 0; ks < 8; ++ks) {
    bf16x8 bb = *(const bf16x8*)(T + ((rb << 9) | ((ks * 64 + lk * 16) ^ ((rb & 7) << 4))));
#pragma unroll
    for (int ri = 0; ri < 5; ++ri) {
      int ra = ri * 16 + lr;
      bf16x8 a = *(const bf16x8*)(T + ((ra << 9) | ((ks * 64 + lk * 16) ^ ((ra & 7) << 4))));
      acc[ri] = __builtin_amdgcn_mfma_f32_16x16x32_bf16(a, bb, acc[ri], 0, 0, 0);
    }
  }
  float* dst = G1P + bid * 5120;
#pragma unroll
  for (int ri = 0; ri < 5; ++ri)
#pragma unroll
    for (int r = 0; r < 4; ++r)
      dst[(ri * 16 + lk * 4 + r) * 64 + w * 16 + lr] = acc[ri][r];
}

// ---------------- K3: reduce G1 partials ----------------
__global__ void k_gred1(const float* __restrict__ G1P, float* __restrict__ G1) {
  int e = blockIdx.x * 256 + threadIdx.x;  // 20 blocks
  float s = 0.f;
  for (int p = 0; p < 256; ++p) s += G1P[p * 5120 + e];
  G1[e] = s;
}

// ---------------- K4: BN2 scale/shift from G1e ----------------
__global__ void k_fin2(const float* __restrict__ G1, const float* __restrict__ w2,
                       const float* __restrict__ b2, const float* __restrict__ g2,
                       const float* __restrict__ be2, float* __restrict__ SC2) {
  int o = blockIdx.x, l = threadIdx.x;  // 128 blocks x 64
  __shared__ float wv[64];
  wv[l] = w2[o * 64 + l];
  __syncthreads();
  float h = 0.f;
  const float* gr = G1 + l * 64;
  for (int k = 0; k < 64; ++k) h = fmaf(gr[k], wv[k], h);
  float q = wv[l] * h;
  float dw = wv[l] * G1[4096 + l];  // cs1 row
  for (int off = 32; off; off >>= 1) { q += __shfl_xor(q, off); dw += __shfl_xor(dw, off); }
  if (l == 0) {
    float bb = b2[o];
    float sumY = dw + NSf * bb;
    float sumY2 = q + 2.f * bb * dw + NSf * bb * bb;
    float m = sumY / NSf;
    float v = sumY2 / NSf - m * m;
    float sc = g2[o] * rsqrtf(v + EPS);
    float sh = be2[o] - m * sc;
    SC2[o] = sc;
    SC2[128 + o] = sc * bb + sh;  // fold conv bias into shift
  }
}

// ---------------- K5: conv2 MFMA + BN2 + ReLU -> x2t bf16 ----------------
__global__ __launch_bounds__(256) void k_conv2(const float* __restrict__ src,
                                               const float* __restrict__ eff,
                                               const u16* __restrict__ w2bf,
                                               const float* __restrict__ SC2,
                                               u16* __restrict__ y2t) {
  __shared__ char WT[16384];  // W2 [128o][64c] bf16 swizzled
  __shared__ char XT[32768];  // x1 [256p][64c] bf16 swizzled
  int t = threadIdx.x, bid = blockIdx.x;
  int lane = t & 63, lr = lane & 15, lk = lane >> 4;
  int w = __builtin_amdgcn_readfirstlane(t >> 6);
#pragma unroll
  for (int i = 0; i < 4; ++i) {
    int s = i * 4096 + t * 16;
    int o = s >> 7, cb = s & 127;
    gl16((const char*)w2bf + ((o << 7) | (cb ^ ((o & 7) << 4))), WT + s);
  }
  int P = bid * 256 + t, b = P >> 13, n = P & 8191;
  float s0 = src[(b * 3 + 0) * 8192 + n];
  float s1 = src[(b * 3 + 1) * 8192 + n];
  float s2 = src[(b * 3 + 2) * 8192 + n];
#pragma unroll
  for (int i = 0; i < 8; ++i) {
    u16x8 pk;
#pragma unroll
    for (int e = 0; e < 8; ++e) {
      int c = i * 8 + e;
      pk[e] = f2b(fmaxf(fmaf(eff[c * 3], s0, fmaf(eff[c * 3 + 1], s1,
                        fmaf(eff[c * 3 + 2], s2, eff[192 + c]))), 0.f));
    }
    *(u16x8*)(XT + ((t << 7) | ((i * 16) ^ ((t & 7) << 4)))) = pk;
  }
  __syncthreads();
  int o0w = (w & 1) * 64, p0w = (w >> 1) * 128;
  f32x4 acc[4][8];
#pragma unroll
  for (int i = 0; i < 4; ++i)
#pragma unroll
    for (int j = 0; j < 8; ++j) acc[i][j] = (f32x4){0.f, 0.f, 0.f, 0.f};
#pragma unroll
  for (int kk = 0; kk < 2; ++kk) {
    bf16x8 a[4], bb[8];
#pragma unroll
    for (int i = 0; i < 4; ++i) {
      int row = o0w + i * 16 + lr;
      a[i] = *(const bf16x8*)(WT + ((row << 7) | ((kk * 64 + lk * 16) ^ ((row & 7) << 4))));
    }
#pragma unroll
    for (int j = 0; j < 8; ++j) {
      int prow = p0w + j * 16 + lr;
      bb[j] = *(const bf16x8*)(XT + ((prow << 7) | ((kk * 64 + lk * 16) ^ ((prow & 7) << 4))));
    }
#pragma unroll
    for (int i = 0; i < 4; ++i)
#pragma unroll
      for (int j = 0; j < 8; ++j)
        acc[i][j] = __builtin_amdgcn_mfma_f32_16x16x32_bf16(a[i], bb[j], acc[i][j], 0, 0, 0);
  }
#pragma unroll
  for (int i = 0; i < 4; ++i) {
    int obch = o0w + i * 16 + lk * 4;
    float4 sc4 = *(const float4*)&SC2[obch];
    float4 sh4 = *(const float4*)&SC2[128 + obch];
#pragma unroll
    for (int j = 0; j < 8; ++j) {
      int p = p0w + j * 16 + lr;
      u16x4 pk;
      pk[0] = f2b(fmaxf(fmaf(sc4.x, acc[i][j][0], sh4.x), 0.f));
      pk[1] = f2b(fmaxf(fmaf(sc4.y, acc[i][j][1], sh4.y), 0.f));
      pk[2] = f2b(fmaxf(fmaf(sc4.z, acc[i][j][2], sh4.z), 0.f));
      pk[3] = f2b(fmaxf(fmaf(sc4.w, acc[i][j][3], sh4.w), 0.f));
      *(u16x4*)(y2t + (size_t)(bid * 256 + p) * 128 + obch) = pk;
    }
  }
}

// ---------------- K6: conv3 — W in regs, X streamed, stats+max in epilogue ---
__device__ __forceinline__ void stage_x(const u16* __restrict__ xit, char* dst, int t) {
#pragma unroll
  for (int q = 0; q < 4; ++q) {
    int s = q * 4096 + t * 16;
    int row = s >> 8, colb = s & 255;
    gl16((const char*)xit + row * 256 + (colb ^ ((row & 7) << 4)), dst + s);
  }
}

__global__ __launch_bounds__(256, 2) void k_conv3(const u16* __restrict__ x2t,
                                                  const u16* __restrict__ w3bf,
                                                  float* __restrict__ SUMP,
                                                  float* __restrict__ SQP,
                                                  float* __restrict__ MAXP) {
  __shared__ char XS[32768];  // 2 x 16KB X tiles [64n][128k], swizzled
  int t = threadIdx.x, lane = t & 63;
  int l15 = lane & 15, l4 = lane >> 4;
  int w = __builtin_amdgcn_readfirstlane(t >> 6);
  int bid = blockIdx.x;             // 512 = 4 ob * 8 b * 16 nc
  int ob = bid & 3, b = (bid >> 2) & 7, nc = bid >> 5;
  int o0 = ob * 256 + w * 64;
  const u16* xbase = x2t + ((size_t)(b * 8192 + nc * 512)) * 128;
  // W fragments: wave-owned o64, 16 x bf16x8, loaded once
  bf16x8 af[16];
#pragma unroll
  for (int i = 0; i < 4; ++i)
#pragma unroll
    for (int kk = 0; kk < 4; ++kk)
      af[i * 4 + kk] = *(const bf16x8*)((const char*)w3bf +
          (size_t)(o0 + i * 16 + l15) * 256 + kk * 64 + l4 * 16);
  f32x4 acc[4][4];
  float rmax[4][4], rsum[4][4], rsq[4][4];
#pragma unroll
  for (int i = 0; i < 4; ++i)
#pragma unroll
    for (int j = 0; j < 4; ++j) {
      acc[i][j] = (f32x4){0.f, 0.f, 0.f, 0.f};
      rmax[i][j] = -1e30f; rsum[i][j] = 0.f; rsq[i][j] = 0.f;
    }
  stage_x(xbase, XS, t);
  __syncthreads();
  for (int it = 0; it < 8; ++it) {
    if (it < 7) stage_x(xbase + (size_t)(it + 1) * 8192, XS + ((it + 1) & 1) * 16384, t);
    const char* xb = XS + (it & 1) * 16384;
#pragma unroll
    for (int kk = 0; kk < 4; ++kk) {
      bf16x8 bf[4];
#pragma unroll
      for (int j = 0; j < 4; ++j) {
        int row = j * 16 + l15;
        bf[j] = *(const bf16x8*)(xb + row * 256 + ((kk * 64 + (l4 << 4)) ^ ((lane & 7) << 4)));
      }
#pragma unroll
      for (int i = 0; i < 4; ++i)
#pragma unroll
        for (int j = 0; j < 4; ++j)
          acc[i][j] = __builtin_amdgcn_mfma_f32_16x16x32_bf16(af[i * 4 + kk], bf[j], acc[i][j], 0, 0, 0);
    }
    // epilogue: fold this n64 tile into running sum/sq/max, reset acc
#pragma unroll
    for (int i = 0; i < 4; ++i)
#pragma unroll
      for (int j = 0; j < 4; ++j)
#pragma unroll
        for (int r = 0; r < 4; ++r) {
          float v = acc[i][j][r];
          rmax[i][r] = fmaxf(rmax[i][r], v);
          rsum[i][r] += v;
          rsq[i][r] = fmaf(v, v, rsq[i][r]);
          acc[i][j][r] = 0.f;
        }
    __syncthreads();
  }
  // reduce across the 16 n-lanes, one writer per o (no atomics anywhere)
#pragma unroll
  for (int i = 0; i < 4; ++i)
#pragma unroll
    for (int r = 0; r < 4; ++r) {
      float mx = rmax[i][r], s = rsum[i][r], q = rsq[i][r];
#pragma unroll
      for (int off = 1; off <= 8; off <<= 1) {
        mx = fmaxf(mx, __shfl_xor(mx, off));
        s += __shfl_xor(s, off);
        q += __shfl_xor(q, off);
      }
      if (l15 == 0) {
        int o = o0 + i * 16 + l4 * 4 + r;
        int sl = (nc * 8 + b) * 1024 + o;
        SUMP[sl] = s; SQP[sl] = q; MAXP[sl] = mx;
      }
    }
}

// ---------------- K7: reduce partials, finalize BN3 + pool ----------------
__global__ void k_pool(const float* __restrict__ SUMP, const float* __restrict__ SQP,
                       const float* __restrict__ MAXP, const float* __restrict__ b3,
                       const float* __restrict__ g3, const float* __restrict__ be3,
                       float* __restrict__ POOL) {
  int idx = blockIdx.x * 256 + threadIdx.x;  // 8192 = b*1024+o
  int b = idx >> 10, o = idx & 1023;
  float s = 0.f, q = 0.f;
  for (int p = 0; p < 128; ++p) {
    s += SUMP[p * 1024 + o];
    q += SQP[p * 1024 + o];
  }
  float mx = -1e30f;
  for (int ncn = 0; ncn < 16; ++ncn) mx = fmaxf(mx, MAXP[(ncn * 8 + b) * 1024 + o]);
  float bb = b3[o];
  float sumY = s + NSf * bb;
  float sumY2 = q + 2.f * bb * s + NSf * bb * bb;
  float m = sumY / NSf;
  float v = sumY2 / NSf - m * m;
  float sc = g3[o] * rsqrtf(v + EPS);
  float sh = be3[o] - m * sc;
  POOL[idx] = fmaxf(fmaf(sc, mx + bb, sh), 0.f);
}

// ---------------- K8/K9: FC + BN(8) + ReLU ----------------
__global__ void k_fc(const float* __restrict__ xin, const float* __restrict__ w,
                     const float* __restrict__ bias, const float* __restrict__ g,
                     const float* __restrict__ be, float* __restrict__ out,
                     int K, int O) {
  int o = blockIdx.x, lane = threadIdx.x;  // 64 threads
  float yb[8] = {0.f, 0.f, 0.f, 0.f, 0.f, 0.f, 0.f, 0.f};
  for (int j = 0; j < K; j += 64) {
    float wv = w[(size_t)o * K + j + lane];
#pragma unroll
    for (int b = 0; b < 8; ++b) yb[b] = fmaf(wv, xin[b * K + j + lane], yb[b]);
  }
#pragma unroll
  for (int b = 0; b < 8; ++b)
    for (int off = 32; off; off >>= 1) yb[b] += __shfl_xor(yb[b], off);
  if (lane == 0) {
    float y[8];
    float m = 0.f;
#pragma unroll
    for (int b = 0; b < 8; ++b) { y[b] = yb[b] + bias[o]; m += y[b]; }
    m *= 0.125f;
    float v = 0.f;
#pragma unroll
    for (int b = 0; b < 8; ++b) { float d = y[b] - m; v = fmaf(d, d, v); }
    v *= 0.125f;
    float sc = g[o] * rsqrtf(v + EPS);
    float sh = be[o] - m * sc;
#pragma unroll
    for (int b = 0; b < 8; ++b) out[b * O + o] = fmaxf(fmaf(sc, y[b], sh), 0.f);
  }
}

// ---------------- K10: rot/trans heads ----------------
__global__ void k_rot(const float* __restrict__ x, const float* __restrict__ wr,
                      const float* __restrict__ br, const float* __restrict__ wt,
                      const float* __restrict__ bt, float* __restrict__ ROT,
                      float* __restrict__ TRANS) {
  int q = blockIdx.x;  // 96
  int b = q / 12, j = q % 12;
  int lane = threadIdx.x;
  float p = 0.f;
#pragma unroll
  for (int i = 0; i < 4; ++i) {
    int kk = i * 64 + lane;
    float w = (j < 9) ? wr[j * 256 + kk] : wt[(j - 9) * 256 + kk];
    p = fmaf(w, x[b * 256 + kk], p);
  }
  for (int off = 32; off; off >>= 1) p += __shfl_xor(p, off);
  if (lane == 0) {
    if (j < 9)
      ROT[b * 9 + j] = p + br[j] + ((j == 0 || j == 4 || j == 8) ? 1.f : 0.f);
    else
      TRANS[b * 3 + (j - 9)] = p + bt[j - 9];
  }
}

// ---------------- K11: apply transform + dist (block-reduced atomics) --------
__global__ void k_transform(const float* __restrict__ src, const float* __restrict__ tgt,
                            const float* __restrict__ ROT, const float* __restrict__ TRANS,
                            float* __restrict__ out, float* __restrict__ DIST) {
  int bx = blockIdx.x, t = threadIdx.x;
  int b = bx >> 5;
  int n = ((bx & 31) << 8) + t;
  float s0 = src[(b * 3 + 0) * 8192 + n];
  float s1 = src[(b * 3 + 1) * 8192 + n];
  float s2 = src[(b * 3 + 2) * 8192 + n];
  const float* R = ROT + b * 9;
  const float* T = TRANS + b * 3;
  float st[3];
#pragma unroll
  for (int c = 0; c < 3; ++c) {
    st[c] = fmaf(s0, R[0 * 3 + c], fmaf(s1, R[1 * 3 + c], fmaf(s2, R[2 * 3 + c], T[c])));
    out[1 + (b * 3 + c) * 8192 + n] = st[c];
  }
  float tg[3];
#pragma unroll
  for (int i = 0; i < 3; ++i) tg[i] = tgt[(b * 3 + i) * 8192 + n];
  float d[9];
#pragma unroll
  for (int i = 0; i < 3; ++i)
#pragma unroll
    for (int j = 0; j < 3; ++j) {
      float df = st[j] - tg[i];
      d[i * 3 + j] = df * df;
    }
#pragma unroll
  for (int k = 0; k < 9; ++k)
    for (int off = 32; off; off >>= 1) d[k] += __shfl_xor(d[k], off);
  __shared__ float red[4][9];
  int wv = t >> 6;
  if ((t & 63) == 0) {
#pragma unroll
    for (int k = 0; k < 9; ++k) red[wv][k] = d[k];
  }
  __syncthreads();
  if (t < 9) {
    float s = red[0][t] + red[1][t] + red[2][t] + red[3][t];
    atomicAdd(&DIST[b * 9 + t], s);
  }
}

// ---------------- K12: loss ----------------
__global__ void k_loss(const float* __restrict__ DIST, float* __restrict__ out) {
  if (threadIdx.x == 0 && blockIdx.x == 0) {
    float acc = 0.f;
    for (int b = 0; b < 8; ++b) {
      const float* D = DIST + b * 9;
      for (int j = 0; j < 3; ++j)
        acc += fminf(D[j], fminf(D[3 + j], D[6 + j]));
      for (int i = 0; i < 3; ++i)
        acc += fminf(D[i * 3], fminf(D[i * 3 + 1], D[i * 3 + 2]));
    }
    out[0] = acc / 24.f;
  }
}

extern "C" void kernel_launch(void* const* d_in, const int* in_sizes, int n_in,
                              void* d_out, int out_size, void* d_ws, size_t ws_size,
                              hipStream_t stream) {
  const float* src = (const float*)d_in[0];
  const float* tgt = (const float*)d_in[1];
  const float* w1 = (const float*)d_in[2];
  const float* b1 = (const float*)d_in[3];
  const float* w2 = (const float*)d_in[4];
  const float* b2 = (const float*)d_in[5];
  const float* w3 = (const float*)d_in[6];
  const float* b3 = (const float*)d_in[7];
  const float* fw1 = (const float*)d_in[8];
  const float* fb1 = (const float*)d_in[9];
  const float* fw2 = (const float*)d_in[10];
  const float* fb2 = (const float*)d_in[11];
  const float* wr = (const float*)d_in[12];
  const float* br = (const float*)d_in[13];
  const float* wt = (const float*)d_in[14];
  const float* bt = (const float*)d_in[15];
  const float* g1 = (const float*)d_in[16];
  const float* be1 = (const float*)d_in[17];
  const float* g2 = (const float*)d_in[18];
  const float* be2 = (const float*)d_in[19];
  const float* g3 = (const float*)d_in[20];
  const float* be3 = (const float*)d_in[21];
  const float* g4 = (const float*)d_in[22];
  const float* be4 = (const float*)d_in[23];
  const float* g5 = (const float*)d_in[24];
  const float* be5 = (const float*)d_in[25];
  float* out = (float*)d_out;
  float* ws = (float*)d_ws;
  u16* y2t = (u16*)(ws + WS_Y2T);
  u16* w3bf = (u16*)(ws + WS_W3BF);
  u16* w2bf = (u16*)(ws + WS_W2BF);

  k_prep<<<608, 256, 0, stream>>>(w3, w2, src, w3bf, w2bf, ws + WS_SP, ws + WS_DIST);
  k_fin1<<<1, 64, 0, stream>>>(ws + WS_SP, w1, b1, g1, be1, ws + WS_EFF1);
  k_x1stats<<<256, 256, 0, stream>>>(src, ws + WS_EFF1, ws + WS_G1P);
  k_gred1<<<20, 256, 0, stream>>>(ws + WS_G1P, ws + WS_G1);
  k_fin2<<<128, 64, 0, stream>>>(ws + WS_G1, w2, b2, g2, be2, ws + WS_SC2);
  k_conv2<<<256, 256, 0, stream>>>(src, ws + WS_EFF1, w2bf, ws + WS_SC2, y2t);
  k_conv3<<<512, 256, 0, stream>>>(y2t, w3bf, ws + WS_SUMP, ws + WS_SQP, ws + WS_MAXP);
  k_pool<<<32, 256, 0, stream>>>(ws + WS_SUMP, ws + WS_SQP, ws + WS_MAXP, b3, g3, be3,
                                 ws + WS_POOL);
  k_fc<<<512, 64, 0, stream>>>(ws + WS_POOL, fw1, fb1, g4, be4, ws + WS_FC1, 1024, 512);
  k_fc<<<256, 64, 0, stream>>>(ws + WS_FC1, fw2, fb2, g5, be5, ws + WS_FC2, 512, 256);
  k_rot<<<96, 64, 0, stream>>>(ws + WS_FC2, wr, br, wt, bt, ws + WS_ROT, ws + WS_TRANS);
  k_transform<<<256, 256, 0, stream>>>(src, tgt, ws + WS_ROT, ws + WS_TRANS, out,
                                       ws + WS_DIST);
  k_loss<<<1, 64, 0, stream>>>(ws + WS_DIST, out);
}